// Round 3
// baseline (944.643 us; speedup 1.0000x reference)
//
#include <hip/hip_runtime.h>
#include <hip/hip_cooperative_groups.h>
#include <math.h>

namespace cg = cooperative_groups;

#define N_NODES  20000
#define N_EDGES  320000
#define N_GRAPHS 200
#define MAXN     100
#define F_IN     128
#define F_H      256
#define F_L      64
#define P_PAIRS  4950
#define P_PAD    4992                       // P_PAIRS padded to multiple of 64
#define ADJ_SIZE (N_GRAPHS * MAXN * MAXN)   // 2,000,000
#define MU_OFF   ADJ_SIZE
#define LV_OFF   (ADJ_SIZE + N_GRAPHS * F_L)

#define SCAN_NB  ((N_NODES + 255) / 256)    // 79 blocks (fallback path)
#define DEG_NB   ((N_EDGES + 255) / 256)    // 1250 blocks (fallback path)

static inline int ceil_div(int a, int b) { return (a + b - 1) / b; }

typedef __attribute__((ext_vector_type(8))) short bf16x8;   // 4 VGPRs
typedef __attribute__((ext_vector_type(4))) float f32x4;    // MFMA acc

// fp32 -> bf16 round-to-nearest-even
static __device__ inline unsigned short f2bf(float f) {
    union { float f; unsigned u; } v; v.f = f;
    unsigned r = (v.u + 0x7FFFu + ((v.u >> 16) & 1u)) >> 16;
    return (unsigned short)r;
}
static __device__ inline float bf2f(unsigned short s) {
    union { unsigned u; float f; } v; v.u = (unsigned)s << 16; return v.f;
}
static __device__ inline float4 ubf4(ushort4 u) {
    float4 f;
    f.x = bf2f(u.x); f.y = bf2f(u.y); f.z = bf2f(u.z); f.w = bf2f(u.w);
    return f;
}

// ================================================================ MEGA KERNEL
// One cooperative kernel; phases separated by grid.sync().
// P0 zero(ws scratch + adj) + prepack W1/W2/D3
// P1 degree histogram          P2 per-512-tile scan (+dinv)
// P3 tile-offset add           P4 CSR fill + xs cast
// P5 fused gather1+GEMM1       P6 gather2
// P7 GEMM2 + fused mean-pool   P8 head/dec1/dec2 (2 graphs/block)
// P9 decoder D3 GEMM + fused adjacency scatter (both triangles)

#define PP_S1  32768                       // W1: 128*256
#define PP_S2  98304                       // + W2: 256*256
#define PP_END 1376256                     // + D3: 256*4992
#define MG_NZ0 22816                       // (deg+fill+hg bytes)/16 = 365056/16
#define MG_NZ1 522816                      // + adj 2,000,000/4
#define MG_NVBZ 1022                       // ceil(522816/512)
#define MG_NVBPP 2688                      // PP_END/512
#define MG_NVB0 (MG_NVBZ + MG_NVBPP)
#define MG_SCAN_T 40                       // ceil(20000/512)

struct MegaArgs {
    const float* x; const int* src; const int* dst; const int* batch; const float* eps;
    const float* W1; const float* b1; const float* W2; const float* b2;
    const float* Wmu; const float* bmu; const float* Wlv; const float* blv;
    const float* D1; const float* db1; const float* D2; const float* db2;
    const float* D3; const float* db3;
    int* deg; int* fill; float* hg; int* rowptr; int* bsum; int* col; float* dinv;
    unsigned short* xs; unsigned short* W1p; unsigned short* W2p; unsigned short* D3p;
    unsigned short* h1s; unsigned short* g2; unsigned short* d2b;
    float* out;
};

__global__ __launch_bounds__(512) void k_mega(MegaArgs A) {
    cg::grid_group grd = cg::this_grid();
    const int tid = threadIdx.x;
    const int bid = blockIdx.x;
    const int gsz = gridDim.x;
    __shared__ __align__(16) char smem[35840];

    // ---------------- P0: zero scratch+adj, prepack weights
    for (int vb = bid; vb < MG_NVB0; vb += gsz) {
        if (vb < MG_NVBZ) {
            int idx = vb * 512 + tid;
            if (idx < MG_NZ0) ((float4*)A.deg)[idx] = float4{0.f, 0.f, 0.f, 0.f};
            else if (idx < MG_NZ1) ((float4*)A.out)[idx - MG_NZ0] = float4{0.f, 0.f, 0.f, 0.f};
        } else {
            int pid = (vb - MG_NVBZ) * 512 + tid;
            const float* W; unsigned short* Bp; int N, NP, t;
            if (pid < PP_S1)      { t = pid;          W = A.W1; Bp = A.W1p; N = 256;     NP = 256; }
            else if (pid < PP_S2) { t = pid - PP_S1;  W = A.W2; Bp = A.W2p; N = 256;     NP = 256; }
            else                  { t = pid - PP_S2;  W = A.D3; Bp = A.D3p; N = P_PAIRS; NP = P_PAD; }
            int j    = t & 7;
            int lane = (t >> 3) & 63;
            int tile = t >> 9;
            int NT = NP >> 4;
            int nt = tile % NT;
            int kt = tile / NT;
            int k = kt * 32 + (lane >> 4) * 8 + j;
            int n = nt * 16 + (lane & 15);
            Bp[t] = (n < N) ? f2bf(W[(size_t)k * N + n]) : (unsigned short)0;
        }
    }
    __threadfence(); grd.sync();

    // ---------------- P1: degree histogram (320000 = 625*512 exact)
    for (int vb = bid; vb < 625; vb += gsz) {
        int e = vb * 512 + tid;
        atomicAdd(A.deg + A.dst[e], 1);
    }
    __threadfence(); grd.sync();

    // ---------------- P2: per-tile inclusive scan (+dinv)
    if (bid < MG_SCAN_T) {
        int* tmp = (int*)smem;
        int i = bid * 512 + tid;
        int v = (i < N_NODES) ? A.deg[i] : 0;
        if (i < N_NODES) A.dinv[i] = rsqrtf((float)v + 1.0f);   // +1 self-loop
        tmp[tid] = v;
        __syncthreads();
        #pragma unroll
        for (int off = 1; off < 512; off <<= 1) {
            int t = (tid >= off) ? tmp[tid - off] : 0;
            __syncthreads();
            tmp[tid] += t;
            __syncthreads();
        }
        if (i < N_NODES) A.rowptr[i + 1] = tmp[tid];
        if (tid == 511) A.bsum[bid] = tmp[511];
        if (bid == 0 && tid == 0) A.rowptr[0] = 0;
    }
    __threadfence(); grd.sync();

    // ---------------- P3: add tile offsets
    if (bid < MG_SCAN_T) {
        int* soff = (int*)smem;
        if (tid == 0) {
            int s = 0;
            #pragma unroll
            for (int t = 0; t < MG_SCAN_T; ++t) s += (t < bid) ? A.bsum[t] : 0;
            soff[0] = s;
        }
        __syncthreads();
        int i = bid * 512 + tid;
        if (i < N_NODES) A.rowptr[i + 1] += soff[0];
    }
    __threadfence(); grd.sync();

    // ---------------- P4: CSR fill + xs cast
    for (int vb = bid; vb < 1875; vb += gsz) {
        if (vb < 625) {
            int e = vb * 512 + tid;
            int d = A.dst[e];
            int pos = A.rowptr[d] + atomicAdd(A.fill + d, 1);
            A.col[pos] = A.src[e];
        } else {
            int t4 = (vb - 625) * 512 + tid;      // < 640000 exact
            int v = t4 >> 5;
            float dv = A.dinv[v];
            float4 val = ((const float4*)A.x)[t4];
            ushort4 o;
            o.x = f2bf(val.x * dv); o.y = f2bf(val.y * dv);
            o.z = f2bf(val.z * dv); o.w = f2bf(val.w * dv);
            ((ushort4*)A.xs)[t4] = o;
        }
    }
    __threadfence(); grd.sync();

    // ---------------- P5: fused layer1 (gather x into LDS tile + MFMA)
    for (int vb = bid; vb < 313; vb += gsz) {
        char* Ab = smem;
        const int lane = tid & 63;
        const int w    = tid >> 6;
        for (int s = 0; s < 8; ++s) {
            int slot = w * 8 + s;
            int v = vb * 64 + slot;
            ushort2 ob; ob.x = 0; ob.y = 0;
            if (v < N_NODES) {
                int beg = A.rowptr[v], end = A.rowptr[v + 1];
                float2 a0 = make_float2(0.f, 0.f), a1 = make_float2(0.f, 0.f);
                int i = beg;
                for (; i + 8 <= end; i += 8) {
                    int s0 = A.col[i + 0], s1 = A.col[i + 1], s2 = A.col[i + 2], s3 = A.col[i + 3];
                    int s4 = A.col[i + 4], s5 = A.col[i + 5], s6 = A.col[i + 6], s7 = A.col[i + 7];
                    ushort2 u0 = ((const ushort2*)(A.xs + (size_t)s0 * F_IN))[lane];
                    ushort2 u1 = ((const ushort2*)(A.xs + (size_t)s1 * F_IN))[lane];
                    ushort2 u2 = ((const ushort2*)(A.xs + (size_t)s2 * F_IN))[lane];
                    ushort2 u3 = ((const ushort2*)(A.xs + (size_t)s3 * F_IN))[lane];
                    ushort2 u4 = ((const ushort2*)(A.xs + (size_t)s4 * F_IN))[lane];
                    ushort2 u5 = ((const ushort2*)(A.xs + (size_t)s5 * F_IN))[lane];
                    ushort2 u6 = ((const ushort2*)(A.xs + (size_t)s6 * F_IN))[lane];
                    ushort2 u7 = ((const ushort2*)(A.xs + (size_t)s7 * F_IN))[lane];
                    a0.x += bf2f(u0.x) + bf2f(u2.x) + bf2f(u4.x) + bf2f(u6.x);
                    a0.y += bf2f(u0.y) + bf2f(u2.y) + bf2f(u4.y) + bf2f(u6.y);
                    a1.x += bf2f(u1.x) + bf2f(u3.x) + bf2f(u5.x) + bf2f(u7.x);
                    a1.y += bf2f(u1.y) + bf2f(u3.y) + bf2f(u5.y) + bf2f(u7.y);
                }
                for (; i + 4 <= end; i += 4) {
                    int s0 = A.col[i + 0], s1 = A.col[i + 1], s2 = A.col[i + 2], s3 = A.col[i + 3];
                    ushort2 u0 = ((const ushort2*)(A.xs + (size_t)s0 * F_IN))[lane];
                    ushort2 u1 = ((const ushort2*)(A.xs + (size_t)s1 * F_IN))[lane];
                    ushort2 u2 = ((const ushort2*)(A.xs + (size_t)s2 * F_IN))[lane];
                    ushort2 u3 = ((const ushort2*)(A.xs + (size_t)s3 * F_IN))[lane];
                    a0.x += bf2f(u0.x) + bf2f(u2.x); a0.y += bf2f(u0.y) + bf2f(u2.y);
                    a1.x += bf2f(u1.x) + bf2f(u3.x); a1.y += bf2f(u1.y) + bf2f(u3.y);
                }
                for (; i < end; ++i) {
                    int sv = A.col[i];
                    ushort2 u = ((const ushort2*)(A.xs + (size_t)sv * F_IN))[lane];
                    a0.x += bf2f(u.x); a0.y += bf2f(u.y);
                }
                ushort2 uv = ((const ushort2*)(A.xs + (size_t)v * F_IN))[lane];
                float dv = A.dinv[v];
                ob.x = f2bf(dv * (a0.x + a1.x + bf2f(uv.x)));
                ob.y = f2bf(dv * (a0.y + a1.y + bf2f(uv.y)));
            }
            int byteoff = (slot * 256 + lane * 4) ^ ((slot & 7) << 4);
            *(ushort2*)(Ab + byteoff) = ob;
        }
        __syncthreads();

        const int rowgrp = w >> 2;      // 0..1
        const int colgrp = w & 3;       // 0..3
        const int quad = lane >> 4;
        const int l15  = lane & 15;
        const int r0 = rowgrp * 32 + l15;
        const int r1 = r0 + 16;

        f32x4 acc[2][4];
        #pragma unroll
        for (int i = 0; i < 2; ++i)
            #pragma unroll
            for (int nt = 0; nt < 4; ++nt) acc[i][nt] = (f32x4){0.f, 0.f, 0.f, 0.f};

        #pragma unroll
        for (int kt = 0; kt < 4; ++kt) {
            int c = kt * 64 + quad * 16;
            bf16x8 a0 = *(const bf16x8*)(Ab + ((r0 * 256 + c) ^ ((r0 & 7) << 4)));
            bf16x8 a1 = *(const bf16x8*)(Ab + ((r1 * 256 + c) ^ ((r1 & 7) << 4)));
            #pragma unroll
            for (int nt = 0; nt < 4; ++nt) {
                bf16x8 b = *(const bf16x8*)(A.W1p + (((size_t)kt * 16 + colgrp * 4 + nt) * 64 + lane) * 8);
                acc[0][nt] = __builtin_amdgcn_mfma_f32_16x16x32_bf16(a0, b, acc[0][nt], 0, 0, 0);
                acc[1][nt] = __builtin_amdgcn_mfma_f32_16x16x32_bf16(a1, b, acc[1][nt], 0, 0, 0);
            }
        }

        #pragma unroll
        for (int i = 0; i < 2; ++i) {
            #pragma unroll
            for (int r = 0; r < 4; ++r) {
                int gm = vb * 64 + rowgrp * 32 + i * 16 + quad * 4 + r;
                if (gm < N_NODES) {
                    float dv = A.dinv[gm];
                    #pragma unroll
                    for (int nt = 0; nt < 4; ++nt) {
                        int gn = colgrp * 64 + nt * 16 + l15;
                        float s = acc[i][nt][r] + A.b1[gn];
                        A.h1s[(size_t)gm * F_H + gn] = f2bf(fmaxf(s, 0.0f) * dv);
                    }
                }
            }
        }
        __syncthreads();
    }
    __threadfence(); grd.sync();

    // ---------------- P6: gather2 (h1s -> g2)
    for (int vb = bid; vb < 5000; vb += gsz) {
        float4* part = (float4*)smem;       // [4][64]
        int w = tid >> 6;
        int nl = w >> 1;
        int half = w & 1;
        int v = vb * 4 + nl;
        int lane = tid & 63;
        int beg = A.rowptr[v], end = A.rowptr[v + 1];
        int mid = beg + ((end - beg) >> 1);
        int lo = half ? mid : beg;
        int hi = half ? end : mid;
        float4 a0 = make_float4(0.f, 0.f, 0.f, 0.f);
        float4 a1 = make_float4(0.f, 0.f, 0.f, 0.f);
        int i = lo;
        for (; i + 8 <= hi; i += 8) {
            int s0 = A.col[i + 0], s1 = A.col[i + 1], s2 = A.col[i + 2], s3 = A.col[i + 3];
            int s4 = A.col[i + 4], s5 = A.col[i + 5], s6 = A.col[i + 6], s7 = A.col[i + 7];
            float4 h0 = ubf4(((const ushort4*)(A.h1s + (size_t)s0 * F_H))[lane]);
            float4 h1 = ubf4(((const ushort4*)(A.h1s + (size_t)s1 * F_H))[lane]);
            float4 h2 = ubf4(((const ushort4*)(A.h1s + (size_t)s2 * F_H))[lane]);
            float4 h3 = ubf4(((const ushort4*)(A.h1s + (size_t)s3 * F_H))[lane]);
            float4 h4 = ubf4(((const ushort4*)(A.h1s + (size_t)s4 * F_H))[lane]);
            float4 h5 = ubf4(((const ushort4*)(A.h1s + (size_t)s5 * F_H))[lane]);
            float4 h6 = ubf4(((const ushort4*)(A.h1s + (size_t)s6 * F_H))[lane]);
            float4 h7 = ubf4(((const ushort4*)(A.h1s + (size_t)s7 * F_H))[lane]);
            a0.x += h0.x + h2.x + h4.x + h6.x; a0.y += h0.y + h2.y + h4.y + h6.y;
            a0.z += h0.z + h2.z + h4.z + h6.z; a0.w += h0.w + h2.w + h4.w + h6.w;
            a1.x += h1.x + h3.x + h5.x + h7.x; a1.y += h1.y + h3.y + h5.y + h7.y;
            a1.z += h1.z + h3.z + h5.z + h7.z; a1.w += h1.w + h3.w + h5.w + h7.w;
        }
        for (; i + 4 <= hi; i += 4) {
            int s0 = A.col[i + 0], s1 = A.col[i + 1], s2 = A.col[i + 2], s3 = A.col[i + 3];
            float4 h0 = ubf4(((const ushort4*)(A.h1s + (size_t)s0 * F_H))[lane]);
            float4 h1 = ubf4(((const ushort4*)(A.h1s + (size_t)s1 * F_H))[lane]);
            float4 h2 = ubf4(((const ushort4*)(A.h1s + (size_t)s2 * F_H))[lane]);
            float4 h3 = ubf4(((const ushort4*)(A.h1s + (size_t)s3 * F_H))[lane]);
            a0.x += h0.x + h2.x; a0.y += h0.y + h2.y; a0.z += h0.z + h2.z; a0.w += h0.w + h2.w;
            a1.x += h1.x + h3.x; a1.y += h1.y + h3.y; a1.z += h1.z + h3.z; a1.w += h1.w + h3.w;
        }
        for (; i < hi; ++i) {
            int s = A.col[i];
            float4 h = ubf4(((const ushort4*)(A.h1s + (size_t)s * F_H))[lane]);
            a0.x += h.x; a0.y += h.y; a0.z += h.z; a0.w += h.w;
        }
        if (half) part[nl * 64 + lane] = make_float4(a0.x + a1.x, a0.y + a1.y,
                                                    a0.z + a1.z, a0.w + a1.w);
        __syncthreads();
        if (!half) {
            float4 p = part[nl * 64 + lane];
            float dv = A.dinv[v];
            float4 hv = ubf4(((const ushort4*)(A.h1s + (size_t)v * F_H))[lane]);
            float ox = dv * (a0.x + a1.x + p.x + hv.x);
            float oy = dv * (a0.y + a1.y + p.y + hv.y);
            float oz = dv * (a0.z + a1.z + p.z + hv.z);
            float ow = dv * (a0.w + a1.w + p.w + hv.w);
            ushort4 ob;
            ob.x = f2bf(ox); ob.y = f2bf(oy); ob.z = f2bf(oz); ob.w = f2bf(ow);
            ((ushort4*)A.g2)[(size_t)v * 64 + lane] = ob;
        }
        __syncthreads();
    }
    __threadfence(); grd.sync();

    // ---------------- P7: GEMM2 + fused mean-pool sums (8-wave, 512 thr)
    for (int vb = bid; vb < 628; vb += gsz) {
        float* sm = (float*)smem;                 // [128][68]
        int* gb = (int*)(smem + 128 * 68 * 4);    // [128]
        const int vbx = vb & 3;
        const int vby = vb >> 2;                  // 0..156
        const int lane = tid & 63;
        const int w    = tid >> 6;
        const int rw   = w >> 1;                  // 0..3
        const int cgp  = w & 1;                   // 0..1
        const int quad = lane >> 4;
        const int l15  = lane & 15;
        const int bm   = vby * 128 + rw * 32;

        if (tid < 128) {
            int gm = vby * 128 + tid;
            gb[tid] = (gm < N_NODES) ? A.batch[gm] : -1;
        }

        int m0 = bm + l15;
        int m1 = m0 + 16;
        int m0c = min(m0, N_NODES - 1), m1c = min(m1, N_NODES - 1);

        f32x4 acc[2][2];
        #pragma unroll
        for (int i = 0; i < 2; ++i)
            #pragma unroll
            for (int j = 0; j < 2; ++j) acc[i][j] = (f32x4){0.f, 0.f, 0.f, 0.f};

        #pragma unroll
        for (int kt = 0; kt < 8; ++kt) {
            bf16x8 a0 = *(const bf16x8*)(A.g2 + (size_t)m0c * F_H + kt * 32 + quad * 8);
            bf16x8 a1 = *(const bf16x8*)(A.g2 + (size_t)m1c * F_H + kt * 32 + quad * 8);
            #pragma unroll
            for (int j = 0; j < 2; ++j) {
                int ntg = vbx * 4 + cgp * 2 + j;
                bf16x8 b = *(const bf16x8*)(A.W2p + (((size_t)kt * 16 + ntg) * 64 + lane) * 8);
                acc[0][j] = __builtin_amdgcn_mfma_f32_16x16x32_bf16(a0, b, acc[0][j], 0, 0, 0);
                acc[1][j] = __builtin_amdgcn_mfma_f32_16x16x32_bf16(a1, b, acc[1][j], 0, 0, 0);
            }
        }

        #pragma unroll
        for (int i = 0; i < 2; ++i) {
            #pragma unroll
            for (int r = 0; r < 4; ++r) {
                int wrow = rw * 32 + i * 16 + quad * 4 + r;
                #pragma unroll
                for (int j = 0; j < 2; ++j) {
                    int cl = (cgp * 2 + j) * 16 + l15;
                    int gn = vbx * 64 + cl;
                    sm[wrow * 68 + cl] = fmaxf(acc[i][j][r] + A.b2[gn], 0.0f);
                }
            }
        }
        __syncthreads();

        {   // segmented per-graph reduction: 8 chunks x 16 rows, 64 cols
            int c  = tid & 63;
            int r0 = (tid >> 6) * 16;
            int gcol = vbx * 64 + c;
            float s = 0.0f;
            int cur = gb[r0];
            #pragma unroll 4
            for (int r = 0; r < 16; ++r) {
                int g = gb[r0 + r];
                if (g != cur) {
                    if (cur >= 0) atomicAdd(A.hg + (size_t)cur * F_H + gcol, s);
                    s = 0.0f; cur = g;
                }
                s += sm[(r0 + r) * 68 + c];
            }
            if (cur >= 0) atomicAdd(A.hg + (size_t)cur * F_H + gcol, s);
        }
        __syncthreads();
    }
    __threadfence(); grd.sync();

    // ---------------- P8: head + dec1 + dec2 (2 graphs per block)
    for (int vb = bid; vb < 100; vb += gsz) {
        const int half = tid >> 8;         // 0/1
        const int t    = tid & 255;
        const int g    = vb * 2 + half;
        float* fs   = (float*)smem;
        float* hgs  = fs + half * 256;            // [2][256]
        float* pp   = fs + 512 + half * 256;      // [2][256]
        float* mulv = fs + 1024 + half * 128;     // [2][128]
        float* zs   = fs + 1280 + half * 64;      // [2][64]
        float* d1s  = fs + 1408 + half * 256;     // [2][256]
        float* sInv = fs + 1920 + half;           // [2]
        if (t == 0) {
            int lo = 0, hi = N_NODES;
            while (lo < hi) { int mid = (lo + hi) >> 1; if (A.batch[mid] < g) lo = mid + 1; else hi = mid; }
            int beg = lo;
            hi = N_NODES;
            while (lo < hi) { int mid = (lo + hi) >> 1; if (A.batch[mid] < g + 1) lo = mid + 1; else hi = mid; }
            sInv[0] = 1.0f / fmaxf((float)(lo - beg), 1.0f);
        }
        __syncthreads();
        hgs[t] = A.hg[(size_t)g * F_H + t] * sInv[0];
        __syncthreads();
        {   // mu/lv: 128 outputs x 2 K-halves
            int o  = t & 127;
            int kh = t >> 7;
            int l = o & 63;
            const float* W = (o < 64) ? A.Wmu : A.Wlv;
            float s = 0.0f;
            int k0 = kh * 128;
            #pragma unroll 8
            for (int k = k0; k < k0 + 128; ++k) s += hgs[k] * W[(size_t)k * F_L + l];
            pp[t] = s;
        }
        __syncthreads();
        if (t < 128) {
            int l = t & 63;
            float s = pp[t] + pp[t + 128] + ((t < 64) ? A.bmu[l] : A.blv[l]);
            A.out[((t < 64) ? MU_OFF : LV_OFF) + g * F_L + l] = s;
            mulv[t] = s;
        }
        __syncthreads();
        if (t < 64)
            zs[t] = mulv[t] + A.eps[g * F_L + t] * expf(0.5f * mulv[64 + t]);
        __syncthreads();
        {   // d1 = relu(z @ D1 + db1): K=64
            float s = A.db1[t];
            #pragma unroll 8
            for (int k = 0; k < F_L; ++k) s += zs[k] * A.D1[(size_t)k * F_H + t];
            d1s[t] = fmaxf(s, 0.0f);
        }
        __syncthreads();
        {   // d2 = relu(d1 @ D2 + db2): K=256
            float s = A.db2[t];
            #pragma unroll 8
            for (int k = 0; k < F_H; ++k) s += d1s[k] * A.D2[(size_t)k * F_H + t];
            A.d2b[(size_t)g * F_H + t] = f2bf(fmaxf(s, 0.0f));
        }
        __syncthreads();
    }
    __threadfence(); grd.sync();

    // ---------------- P9: decoder D3 GEMM + fused adjacency scatter
    for (int vb = bid; vb < 78; vb += gsz) {
        const int lane = tid & 63;
        const int w    = tid >> 6;
        const int quad = lane >> 4;
        const int l15  = lane & 15;
        const int bm   = w * 32;                   // waves cover rows 0..255 (M=200)
        int m0 = bm + l15;
        int m1 = m0 + 16;
        int m0c = min(m0, N_GRAPHS - 1), m1c = min(m1, N_GRAPHS - 1);

        f32x4 acc[2][4];
        #pragma unroll
        for (int i = 0; i < 2; ++i)
            #pragma unroll
            for (int j = 0; j < 4; ++j) acc[i][j] = (f32x4){0.f, 0.f, 0.f, 0.f};

        #pragma unroll
        for (int kt = 0; kt < 8; ++kt) {
            bf16x8 a0 = *(const bf16x8*)(A.d2b + (size_t)m0c * F_H + kt * 32 + quad * 8);
            bf16x8 a1 = *(const bf16x8*)(A.d2b + (size_t)m1c * F_H + kt * 32 + quad * 8);
            #pragma unroll
            for (int j = 0; j < 4; ++j) {
                bf16x8 b = *(const bf16x8*)(A.D3p + (((size_t)kt * 312 + vb * 4 + j) * 64 + lane) * 8);
                acc[0][j] = __builtin_amdgcn_mfma_f32_16x16x32_bf16(a0, b, acc[0][j], 0, 0, 0);
                acc[1][j] = __builtin_amdgcn_mfma_f32_16x16x32_bf16(a1, b, acc[1][j], 0, 0, 0);
            }
        }

        // decode pair index p=gn -> (a,b), upper triangle
        int aa[4], bb[4], gn_[4]; float bias_[4];
        #pragma unroll
        for (int j = 0; j < 4; ++j) {
            int gn = (vb * 4 + j) * 16 + l15;
            gn_[j] = gn;
            int p = (gn < P_PAIRS) ? gn : 0;
            bias_[j] = (gn < P_PAIRS) ? A.db3[gn] : 0.0f;
            int a = (int)floorf((199.0f - sqrtf((float)(39601 - 8 * p))) * 0.5f);
            if (a < 0) a = 0;
            while (a * (199 - a) / 2 > p) --a;
            while ((a + 1) * (198 - a) / 2 <= p) ++a;
            aa[j] = a;
            bb[j] = p - a * (199 - a) / 2 + a + 1;
        }

        #pragma unroll
        for (int i = 0; i < 2; ++i) {
            #pragma unroll
            for (int r = 0; r < 4; ++r) {
                int gm = bm + i * 16 + quad * 4 + r;
                if (gm < N_GRAPHS) {
                    float* og = A.out + (size_t)gm * (MAXN * MAXN);
                    #pragma unroll
                    for (int j = 0; j < 4; ++j) {
                        if (gn_[j] < P_PAIRS) {
                            float s = acc[i][j][r] + bias_[j];
                            float pr = 1.0f / (1.0f + expf(-s));
                            og[aa[j] * MAXN + bb[j]] = pr;
                            og[bb[j] * MAXN + aa[j]] = pr;
                        }
                    }
                }
            }
        }
    }
}

// ================================================================ FALLBACK KERNELS (classic path)
#define PP_NB  (PP_END / 256)              // 5376
__global__ __launch_bounds__(256) void k_deg_prepack(
        const int* __restrict__ dst, int* __restrict__ deg,
        const float* __restrict__ W1, const float* __restrict__ W2,
        const float* __restrict__ D3,
        unsigned short* __restrict__ W1p, unsigned short* __restrict__ W2p,
        unsigned short* __restrict__ D3p) {
    if (blockIdx.x < DEG_NB) {
        int i = blockIdx.x * 256 + threadIdx.x;
        if (i < N_EDGES) atomicAdd(deg + dst[i], 1);
        return;
    }
    int pid = (blockIdx.x - DEG_NB) * 256 + threadIdx.x;
    const float* W; unsigned short* Bp; int N, NP, t;
    if (pid < PP_S1)      { t = pid;          W = W1; Bp = W1p; N = 256;     NP = 256; }
    else if (pid < PP_S2) { t = pid - PP_S1;  W = W2; Bp = W2p; N = 256;     NP = 256; }
    else if (pid < PP_END){ t = pid - PP_S2;  W = D3; Bp = D3p; N = P_PAIRS; NP = P_PAD; }
    else return;
    int j    = t & 7;
    int lane = (t >> 3) & 63;
    int tile = t >> 9;
    int NT = NP >> 4;
    int nt = tile % NT;
    int kt = tile / NT;
    int k = kt * 32 + (lane >> 4) * 8 + j;
    int n = nt * 16 + (lane & 15);
    Bp[t] = (n < N) ? f2bf(W[(size_t)k * N + n]) : (unsigned short)0;
}

__global__ __launch_bounds__(256) void k_scan_local(const int* __restrict__ deg,
                                                    int* __restrict__ rowptr,
                                                    int* __restrict__ bsum,
                                                    float* __restrict__ dinv, int n) {
    __shared__ int tmp[256];
    int i = blockIdx.x * 256 + threadIdx.x;
    int v = (i < n) ? deg[i] : 0;
    if (i < n) dinv[i] = rsqrtf((float)v + 1.0f);
    tmp[threadIdx.x] = v;
    __syncthreads();
    #pragma unroll
    for (int off = 1; off < 256; off <<= 1) {
        int t = (threadIdx.x >= (unsigned)off) ? tmp[threadIdx.x - off] : 0;
        __syncthreads();
        tmp[threadIdx.x] += t;
        __syncthreads();
    }
    if (i < n) rowptr[i + 1] = tmp[threadIdx.x];
    if (threadIdx.x == 255) bsum[blockIdx.x] = tmp[255];
}

__global__ __launch_bounds__(256) void k_scanadd(int* __restrict__ rowptr,
                                                 const int* __restrict__ bsum, int n) {
    __shared__ int red[256];
    int t = threadIdx.x;
    red[t] = (t < (int)blockIdx.x) ? bsum[t] : 0;
    __syncthreads();
    #pragma unroll
    for (int off = 128; off > 0; off >>= 1) {
        if (t < off) red[t] += red[t + off];
        __syncthreads();
    }
    int offv = red[0];
    int i = blockIdx.x * 256 + t;
    if (i < n) rowptr[i + 1] += offv;
    if (blockIdx.x == 0 && t == 0) rowptr[0] = 0;
}

#define CV_END 640000
#define CV_NB  (CV_END / 256)
__global__ __launch_bounds__(256) void k_fill_xs(const int* __restrict__ src,
                                                 const int* __restrict__ dst,
                                                 const int* __restrict__ rowptr,
                                                 int* __restrict__ fill,
                                                 int* __restrict__ col,
                                                 const float* __restrict__ x,
                                                 const float* __restrict__ dinv,
                                                 unsigned short* __restrict__ xs) {
    if (blockIdx.x < DEG_NB) {
        int e = blockIdx.x * 256 + threadIdx.x;
        if (e >= N_EDGES) return;
        int d = dst[e];
        int pos = rowptr[d] + atomicAdd(fill + d, 1);
        col[pos] = src[e];
        return;
    }
    int tid = (blockIdx.x - DEG_NB) * 256 + threadIdx.x;
    if (tid >= CV_END) return;
    int v = tid >> 5;
    float dv = dinv[v];
    float4 val = ((const float4*)x)[tid];
    ushort4 o;
    o.x = f2bf(val.x * dv); o.y = f2bf(val.y * dv);
    o.z = f2bf(val.z * dv); o.w = f2bf(val.w * dv);
    ((ushort4*)xs)[tid] = o;
}

__global__ __launch_bounds__(512) void k_layer1(const unsigned short* __restrict__ xs,
                                                const int* __restrict__ rowptr,
                                                const int* __restrict__ col,
                                                const float* __restrict__ dinv,
                                                const unsigned short* __restrict__ W1p,
                                                const float* __restrict__ bias,
                                                unsigned short* __restrict__ h1s, int M) {
    __shared__ unsigned short At[64 * 128];
    char* Ab = (char*)At;
    const int tid  = threadIdx.x;
    const int lane = tid & 63;
    const int w    = tid >> 6;

    for (int s = 0; s < 8; ++s) {
        int slot = w * 8 + s;
        int v = blockIdx.x * 64 + slot;
        ushort2 ob; ob.x = 0; ob.y = 0;
        if (v < M) {
            int beg = rowptr[v], end = rowptr[v + 1];
            float2 a0 = make_float2(0.f, 0.f), a1 = make_float2(0.f, 0.f);
            int i = beg;
            for (; i + 8 <= end; i += 8) {
                int s0 = col[i + 0], s1 = col[i + 1], s2 = col[i + 2], s3 = col[i + 3];
                int s4 = col[i + 4], s5 = col[i + 5], s6 = col[i + 6], s7 = col[i + 7];
                ushort2 u0 = ((const ushort2*)(xs + (size_t)s0 * F_IN))[lane];
                ushort2 u1 = ((const ushort2*)(xs + (size_t)s1 * F_IN))[lane];
                ushort2 u2 = ((const ushort2*)(xs + (size_t)s2 * F_IN))[lane];
                ushort2 u3 = ((const ushort2*)(xs + (size_t)s3 * F_IN))[lane];
                ushort2 u4 = ((const ushort2*)(xs + (size_t)s4 * F_IN))[lane];
                ushort2 u5 = ((const ushort2*)(xs + (size_t)s5 * F_IN))[lane];
                ushort2 u6 = ((const ushort2*)(xs + (size_t)s6 * F_IN))[lane];
                ushort2 u7 = ((const ushort2*)(xs + (size_t)s7 * F_IN))[lane];
                a0.x += bf2f(u0.x) + bf2f(u2.x) + bf2f(u4.x) + bf2f(u6.x);
                a0.y += bf2f(u0.y) + bf2f(u2.y) + bf2f(u4.y) + bf2f(u6.y);
                a1.x += bf2f(u1.x) + bf2f(u3.x) + bf2f(u5.x) + bf2f(u7.x);
                a1.y += bf2f(u1.y) + bf2f(u3.y) + bf2f(u5.y) + bf2f(u7.y);
            }
            for (; i + 4 <= end; i += 4) {
                int s0 = col[i + 0], s1 = col[i + 1], s2 = col[i + 2], s3 = col[i + 3];
                ushort2 u0 = ((const ushort2*)(xs + (size_t)s0 * F_IN))[lane];
                ushort2 u1 = ((const ushort2*)(xs + (size_t)s1 * F_IN))[lane];
                ushort2 u2 = ((const ushort2*)(xs + (size_t)s2 * F_IN))[lane];
                ushort2 u3 = ((const ushort2*)(xs + (size_t)s3 * F_IN))[lane];
                a0.x += bf2f(u0.x) + bf2f(u2.x); a0.y += bf2f(u0.y) + bf2f(u2.y);
                a1.x += bf2f(u1.x) + bf2f(u3.x); a1.y += bf2f(u1.y) + bf2f(u3.y);
            }
            for (; i < end; ++i) {
                int sv = col[i];
                ushort2 u = ((const ushort2*)(xs + (size_t)sv * F_IN))[lane];
                a0.x += bf2f(u.x); a0.y += bf2f(u.y);
            }
            ushort2 uv = ((const ushort2*)(xs + (size_t)v * F_IN))[lane];
            float dv = dinv[v];
            ob.x = f2bf(dv * (a0.x + a1.x + bf2f(uv.x)));
            ob.y = f2bf(dv * (a0.y + a1.y + bf2f(uv.y)));
        }
        int byteoff = (slot * 256 + lane * 4) ^ ((slot & 7) << 4);
        *(ushort2*)(Ab + byteoff) = ob;
    }
    __syncthreads();

    const int rowgrp = w >> 2;
    const int colgrp = w & 3;
    const int quad = lane >> 4;
    const int l15  = lane & 15;
    const int r0 = rowgrp * 32 + l15;
    const int r1 = r0 + 16;

    f32x4 acc[2][4];
    #pragma unroll
    for (int i = 0; i < 2; ++i)
        #pragma unroll
        for (int nt = 0; nt < 4; ++nt) acc[i][nt] = (f32x4){0.f, 0.f, 0.f, 0.f};

    #pragma unroll
    for (int kt = 0; kt < 4; ++kt) {
        int c = kt * 64 + quad * 16;
        bf16x8 a0 = *(const bf16x8*)(Ab + ((r0 * 256 + c) ^ ((r0 & 7) << 4)));
        bf16x8 a1 = *(const bf16x8*)(Ab + ((r1 * 256 + c) ^ ((r1 & 7) << 4)));
        #pragma unroll
        for (int nt = 0; nt < 4; ++nt) {
            bf16x8 b = *(const bf16x8*)(W1p + (((size_t)kt * 16 + colgrp * 4 + nt) * 64 + lane) * 8);
            acc[0][nt] = __builtin_amdgcn_mfma_f32_16x16x32_bf16(a0, b, acc[0][nt], 0, 0, 0);
            acc[1][nt] = __builtin_amdgcn_mfma_f32_16x16x32_bf16(a1, b, acc[1][nt], 0, 0, 0);
        }
    }

    #pragma unroll
    for (int i = 0; i < 2; ++i) {
        #pragma unroll
        for (int r = 0; r < 4; ++r) {
            int gm = blockIdx.x * 64 + rowgrp * 32 + i * 16 + quad * 4 + r;
            if (gm >= M) continue;
            float dv = dinv[gm];
            #pragma unroll
            for (int nt = 0; nt < 4; ++nt) {
                int gn = colgrp * 64 + nt * 16 + l15;
                float s = acc[i][nt][r] + bias[gn];
                h1s[(size_t)gm * F_H + gn] = f2bf(fmaxf(s, 0.0f) * dv);
            }
        }
    }
}

template<int KDIM, int MODE>
__global__ __launch_bounds__(256) void k_gemm(const unsigned short* __restrict__ A,
                                              const unsigned short* __restrict__ Bp,
                                              void* __restrict__ Y,
                                              const float* __restrict__ bias,
                                              int M, int N, int NP) {
    constexpr int KT = KDIM / 32;
    const int NT   = NP >> 4;
    const int lane = threadIdx.x & 63;
    const int wave = threadIdx.x >> 6;
    const int bm   = blockIdx.y * 128 + wave * 32;
    const int ng0  = blockIdx.x * 4;
    const int quad = lane >> 4;
    const int l15  = lane & 15;

    int m0 = bm + l15;
    int m1 = m0 + 16;
    int m0c = min(m0, M - 1), m1c = min(m1, M - 1);

    f32x4 acc[2][4];
    #pragma unroll
    for (int i = 0; i < 2; ++i)
        #pragma unroll
        for (int nt = 0; nt < 4; ++nt) acc[i][nt] = (f32x4){0.f, 0.f, 0.f, 0.f};

    #pragma unroll
    for (int kt = 0; kt < KT; ++kt) {
        bf16x8 a0 = *(const bf16x8*)(A + (size_t)m0c * KDIM + kt * 32 + quad * 8);
        bf16x8 a1 = *(const bf16x8*)(A + (size_t)m1c * KDIM + kt * 32 + quad * 8);
        #pragma unroll
        for (int nt = 0; nt < 4; ++nt) {
            bf16x8 b = *(const bf16x8*)(Bp + (((size_t)kt * NT + ng0 + nt) * 64 + lane) * 8);
            acc[0][nt] = __builtin_amdgcn_mfma_f32_16x16x32_bf16(a0, b, acc[0][nt], 0, 0, 0);
            acc[1][nt] = __builtin_amdgcn_mfma_f32_16x16x32_bf16(a1, b, acc[1][nt], 0, 0, 0);
        }
    }

    #pragma unroll
    for (int i = 0; i < 2; ++i) {
        #pragma unroll
        for (int r = 0; r < 4; ++r) {
            int gm = bm + i * 16 + quad * 4 + r;
            if (gm >= M) continue;
            #pragma unroll
            for (int nt = 0; nt < 4; ++nt) {
                int gn = ((ng0 + nt) << 4) + l15;
                if (gn >= N) continue;
                float s = acc[i][nt][r] + bias[gn];
                ((float*)Y)[(size_t)gm * N + gn] = 1.0f / (1.0f + expf(-s));
            }
        }
    }
}

__global__ __launch_bounds__(256) void k_gemm_pool(const unsigned short* __restrict__ A,
                                                   const unsigned short* __restrict__ Bp,
                                                   const float* __restrict__ bias,
                                                   const int* __restrict__ batch,
                                                   float* __restrict__ hg, int M) {
    constexpr int KT = F_H / 32;
    const int NT   = F_H >> 4;
    const int lane = threadIdx.x & 63;
    const int wave = threadIdx.x >> 6;
    const int bm   = blockIdx.y * 128 + wave * 32;
    const int ng0  = blockIdx.x * 4;
    const int quad = lane >> 4;
    const int l15  = lane & 15;

    __shared__ float sm[128][68];
    __shared__ int gb[128];
    if (threadIdx.x < 128) {
        int gm = blockIdx.y * 128 + threadIdx.x;
        gb[threadIdx.x] = (gm < M) ? batch[gm] : -1;
    }

    int m0 = bm + l15;
    int m1 = m0 + 16;
    int m0c = min(m0, M - 1), m1c = min(m1, M - 1);

    f32x4 acc[2][4];
    #pragma unroll
    for (int i = 0; i < 2; ++i)
        #pragma unroll
        for (int nt = 0; nt < 4; ++nt) acc[i][nt] = (f32x4){0.f, 0.f, 0.f, 0.f};

    #pragma unroll
    for (int kt = 0; kt < KT; ++kt) {
        bf16x8 a0 = *(const bf16x8*)(A + (size_t)m0c * F_H + kt * 32 + quad * 8);
        bf16x8 a1 = *(const bf16x8*)(A + (size_t)m1c * F_H + kt * 32 + quad * 8);
        #pragma unroll
        for (int nt = 0; nt < 4; ++nt) {
            bf16x8 b = *(const bf16x8*)(Bp + (((size_t)kt * NT + ng0 + nt) * 64 + lane) * 8);
            acc[0][nt] = __builtin_amdgcn_mfma_f32_16x16x32_bf16(a0, b, acc[0][nt], 0, 0, 0);
            acc[1][nt] = __builtin_amdgcn_mfma_f32_16x16x32_bf16(a1, b, acc[1][nt], 0, 0, 0);
        }
    }

    #pragma unroll
    for (int i = 0; i < 2; ++i) {
        #pragma unroll
        for (int r = 0; r < 4; ++r) {
            int wrow = wave * 32 + i * 16 + quad * 4 + r;
            #pragma unroll
            for (int nt = 0; nt < 4; ++nt) {
                int gn = ((ng0 + nt) << 4) + l15;
                sm[wrow][nt * 16 + l15] = fmaxf(acc[i][nt][r] + bias[gn], 0.0f);
            }
        }
    }
    __syncthreads();

    int c  = threadIdx.x & 63;
    int r0 = (threadIdx.x >> 6) * 32;
    int gcol = blockIdx.x * 64 + c;
    float s = 0.0f;
    int cur = gb[r0];
    #pragma unroll 4
    for (int r = 0; r < 32; ++r) {
        int g = gb[r0 + r];
        if (g != cur) {
            if (cur >= 0) atomicAdd(hg + (size_t)cur * F_H + gcol, s);
            s = 0.0f; cur = g;
        }
        s += sm[r0 + r][c];
    }
    if (cur >= 0) atomicAdd(hg + (size_t)cur * F_H + gcol, s);
}

__global__ __launch_bounds__(512) void k_gather2(const unsigned short* __restrict__ Hs,
                                                 const int* __restrict__ rowptr,
                                                 const int* __restrict__ col,
                                                 const float* __restrict__ dinv,
                                                 unsigned short* __restrict__ outp) {
    __shared__ float4 part[4][64];
    int w = threadIdx.x >> 6;
    int nl = w >> 1;
    int half = w & 1;
    int v = blockIdx.x * 4 + nl;
    int lane = threadIdx.x & 63;
    int beg = rowptr[v], end = rowptr[v + 1];
    int mid = beg + ((end - beg) >> 1);
    int lo = half ? mid : beg;
    int hi = half ? end : mid;
    float4 a0 = make_float4(0.f, 0.f, 0.f, 0.f);
    float4 a1 = make_float4(0.f, 0.f, 0.f, 0.f);
    int i = lo;
    for (; i + 8 <= hi; i += 8) {
        int s0 = col[i + 0], s1 = col[i + 1], s2 = col[i + 2], s3 = col[i + 3];
        int s4 = col[i + 4], s5 = col[i + 5], s6 = col[i + 6], s7 = col[i + 7];
        float4 h0 = ubf4(((const ushort4*)(Hs + (size_t)s0 * F_H))[lane]);
        float4 h1 = ubf4(((const ushort4*)(Hs + (size_t)s1 * F_H))[lane]);
        float4 h2 = ubf4(((const ushort4*)(Hs + (size_t)s2 * F_H))[lane]);
        float4 h3 = ubf4(((const ushort4*)(Hs + (size_t)s3 * F_H))[lane]);
        float4 h4 = ubf4(((const ushort4*)(Hs + (size_t)s4 * F_H))[lane]);
        float4 h5 = ubf4(((const ushort4*)(Hs + (size_t)s5 * F_H))[lane]);
        float4 h6 = ubf4(((const ushort4*)(Hs + (size_t)s6 * F_H))[lane]);
        float4 h7 = ubf4(((const ushort4*)(Hs + (size_t)s7 * F_H))[lane]);
        a0.x += h0.x + h2.x + h4.x + h6.x; a0.y += h0.y + h2.y + h4.y + h6.y;
        a0.z += h0.z + h2.z + h4.z + h6.z; a0.w += h0.w + h2.w + h4.w + h6.w;
        a1.x += h1.x + h3.x + h5.x + h7.x; a1.y += h1.y + h3.y + h5.y + h7.y;
        a1.z += h1.z + h3.z + h5.z + h7.z; a1.w += h1.w + h3.w + h5.w + h7.w;
    }
    for (; i + 4 <= hi; i += 4) {
        int s0 = col[i + 0], s1 = col[i + 1], s2 = col[i + 2], s3 = col[i + 3];
        float4 h0 = ubf4(((const ushort4*)(Hs + (size_t)s0 * F_H))[lane]);
        float4 h1 = ubf4(((const ushort4*)(Hs + (size_t)s1 * F_H))[lane]);
        float4 h2 = ubf4(((const ushort4*)(Hs + (size_t)s2 * F_H))[lane]);
        float4 h3 = ubf4(((const ushort4*)(Hs + (size_t)s3 * F_H))[lane]);
        a0.x += h0.x + h2.x; a0.y += h0.y + h2.y; a0.z += h0.z + h2.z; a0.w += h0.w + h2.w;
        a1.x += h1.x + h3.x; a1.y += h1.y + h3.y; a1.z += h1.z + h3.z; a1.w += h1.w + h3.w;
    }
    for (; i < hi; ++i) {
        int s = col[i];
        float4 h = ubf4(((const ushort4*)(Hs + (size_t)s * F_H))[lane]);
        a0.x += h.x; a0.y += h.y; a0.z += h.z; a0.w += h.w;
    }
    if (half) part[nl][lane] = make_float4(a0.x + a1.x, a0.y + a1.y,
                                           a0.z + a1.z, a0.w + a1.w);
    __syncthreads();
    if (!half) {
        float4 p = part[nl][lane];
        float dv = dinv[v];
        float4 hv = ubf4(((const ushort4*)(Hs + (size_t)v * F_H))[lane]);
        float ox = dv * (a0.x + a1.x + p.x + hv.x);
        float oy = dv * (a0.y + a1.y + p.y + hv.y);
        float oz = dv * (a0.z + a1.z + p.z + hv.z);
        float ow = dv * (a0.w + a1.w + p.w + hv.w);
        ushort4 ob;
        ob.x = f2bf(ox); ob.y = f2bf(oy); ob.z = f2bf(oz); ob.w = f2bf(ow);
        ((ushort4*)outp)[(size_t)v * 64 + lane] = ob;
    }
}

__global__ __launch_bounds__(256) void k_head_dec(const float* __restrict__ hg,
                                                  const int* __restrict__ batch,
                                                  const float* __restrict__ Wmu,
                                                  const float* __restrict__ bmu,
                                                  const float* __restrict__ Wlv,
                                                  const float* __restrict__ blv,
                                                  const float* __restrict__ eps,
                                                  const float* __restrict__ D1,
                                                  const float* __restrict__ db1,
                                                  const float* __restrict__ D2,
                                                  const float* __restrict__ db2,
                                                  float* __restrict__ out,
                                                  unsigned short* __restrict__ d2b) {
    int g = blockIdx.x;
    int tid = threadIdx.x;
    __shared__ float hgs[F_H];
    __shared__ float pp[256];
    __shared__ float mulv[128];
    __shared__ float zs[F_L];
    __shared__ float d1s[F_H];
    __shared__ float sInv;
    if (tid == 0) {
        int lo = 0, hi = N_NODES;
        while (lo < hi) { int mid = (lo + hi) >> 1; if (batch[mid] < g) lo = mid + 1; else hi = mid; }
        int beg = lo;
        hi = N_NODES;
        while (lo < hi) { int mid = (lo + hi) >> 1; if (batch[mid] < g + 1) lo = mid + 1; else hi = mid; }
        sInv = 1.0f / fmaxf((float)(lo - beg), 1.0f);
    }
    __syncthreads();
    hgs[tid] = hg[(size_t)g * F_H + tid] * sInv;
    __syncthreads();
    {
        int o    = tid & 127;
        int half = tid >> 7;
        int l = o & 63;
        const float* W = (o < 64) ? Wmu : Wlv;
        float s = 0.0f;
        int k0 = half * 128;
        #pragma unroll 8
        for (int k = k0; k < k0 + 128; ++k) s += hgs[k] * W[(size_t)k * F_L + l];
        pp[tid] = s;
    }
    __syncthreads();
    if (tid < 128) {
        int l = tid & 63;
        float s = pp[tid] + pp[tid + 128] + ((tid < 64) ? bmu[l] : blv[l]);
        out[((tid < 64) ? MU_OFF : LV_OFF) + g * F_L + l] = s;
        mulv[tid] = s;
    }
    __syncthreads();
    if (tid < 64)
        zs[tid] = mulv[tid] + eps[g * F_L + tid] * expf(0.5f * mulv[64 + tid]);
    __syncthreads();
    {
        float s = db1[tid];
        #pragma unroll 8
        for (int k = 0; k < F_L; ++k) s += zs[k] * D1[(size_t)k * F_H + tid];
        d1s[tid] = fmaxf(s, 0.0f);
    }
    __syncthreads();
    {
        float s = db2[tid];
        #pragma unroll 8
        for (int k = 0; k < F_H; ++k) s += d1s[k] * D2[(size_t)k * F_H + tid];
        d2b[(size_t)g * F_H + tid] = f2bf(fmaxf(s, 0.0f));
    }
}

__global__ __launch_bounds__(256) void k_adj(const float* __restrict__ probs,
                                             float* __restrict__ adj) {
    int i = blockIdx.x * blockDim.x + threadIdx.x;
    if (i >= N_GRAPHS * MAXN * (MAXN / 4)) return;
    int b4 = (i % (MAXN / 4)) * 4;
    int a  = (i / (MAXN / 4)) % MAXN;
    int g  = i / (MAXN * (MAXN / 4));
    const float* pg = probs + (size_t)g * P_PAIRS;
    float4 o;
    float* op = (float*)&o;
    #pragma unroll
    for (int c = 0; c < 4; ++c) {
        int b = b4 + c;
        float v = 0.0f;
        if (a != b) {
            int lo = min(a, b), hi = max(a, b);
            int p = lo * (MAXN - 1) - (lo * (lo - 1)) / 2 + (hi - lo - 1);
            v = pg[p];
        }
        op[c] = v;
    }
    ((float4*)adj)[i] = o;
}

// ================================================================ launch
extern "C" void kernel_launch(void* const* d_in, const int* in_sizes, int n_in,
                              void* d_out, int out_size, void* d_ws, size_t ws_size,
                              hipStream_t stream) {
    const float* x    = (const float*)d_in[0];
    const int*   eidx = (const int*)d_in[1];
    const int*   batch= (const int*)d_in[2];
    const float* eps  = (const float*)d_in[3];
    const float* W1   = (const float*)d_in[4];
    const float* b1   = (const float*)d_in[5];
    const float* W2   = (const float*)d_in[6];
    const float* b2   = (const float*)d_in[7];
    const float* Wmu  = (const float*)d_in[8];
    const float* bmu  = (const float*)d_in[9];
    const float* Wlv  = (const float*)d_in[10];
    const float* blv  = (const float*)d_in[11];
    const float* D1   = (const float*)d_in[12];
    const float* db1  = (const float*)d_in[13];
    const float* D2   = (const float*)d_in[14];
    const float* db2  = (const float*)d_in[15];
    const float* D3   = (const float*)d_in[16];
    const float* db3  = (const float*)d_in[17];

    const int* src = eidx;
    const int* dst = eidx + N_EDGES;
    float* out = (float*)d_out;

    // workspace carve-up (deg, fill, hg contiguous -> single zero range)
    char* wsb = (char*)d_ws;
    size_t o = 0;
    auto carve = [&](size_t bytes) { void* p = wsb + o; o += (bytes + 255) & ~255ull; return p; };
    int*   deg    = (int*)  carve(N_NODES * sizeof(int));
    int*   fill   = (int*)  carve(N_NODES * sizeof(int));
    float* hg     = (float*)carve((size_t)N_GRAPHS * F_H * sizeof(float));
    int*   rowptr = (int*)  carve((N_NODES + 1) * sizeof(int));
    int*   bsum   = (int*)  carve(128 * sizeof(int));
    int*   col    = (int*)  carve(N_EDGES * sizeof(int));
    float* dinv   = (float*)carve(N_NODES * sizeof(float));
    unsigned short* xs  = (unsigned short*)carve((size_t)N_NODES * F_IN * sizeof(short));
    unsigned short* W1p = (unsigned short*)carve((size_t)F_IN * F_H * sizeof(short));
    unsigned short* W2p = (unsigned short*)carve((size_t)F_H * F_H * sizeof(short));
    unsigned short* D3p = (unsigned short*)carve((size_t)F_H * P_PAD * sizeof(short));
    unsigned short* h1s = (unsigned short*)carve((size_t)N_NODES * F_H * sizeof(short));
    unsigned short* g2  = (unsigned short*)carve((size_t)N_NODES * F_H * sizeof(short));
    unsigned short* d2b = (unsigned short*)carve((size_t)N_GRAPHS * F_H * sizeof(short));
    float* probs  = (float*)carve((size_t)N_GRAPHS * P_PAIRS * sizeof(float));

    // ---- cooperative mega-kernel (single dispatch)
    static int coopGrid = 0;
    if (coopGrid == 0) {
        int nb = 0;
        if (hipOccupancyMaxActiveBlocksPerMultiprocessor(&nb, k_mega, 512, 0) != hipSuccess || nb < 1)
            nb = 1;
        if (nb > 4) nb = 4;
        coopGrid = nb * 256;
    }
    MegaArgs MA;
    MA.x = x; MA.src = src; MA.dst = dst; MA.batch = batch; MA.eps = eps;
    MA.W1 = W1; MA.b1 = b1; MA.W2 = W2; MA.b2 = b2;
    MA.Wmu = Wmu; MA.bmu = bmu; MA.Wlv = Wlv; MA.blv = blv;
    MA.D1 = D1; MA.db1 = db1; MA.D2 = D2; MA.db2 = db2;
    MA.D3 = D3; MA.db3 = db3;
    MA.deg = deg; MA.fill = fill; MA.hg = hg; MA.rowptr = rowptr; MA.bsum = bsum;
    MA.col = col; MA.dinv = dinv;
    MA.xs = xs; MA.W1p = W1p; MA.W2p = W2p; MA.D3p = D3p;
    MA.h1s = h1s; MA.g2 = g2; MA.d2b = d2b;
    MA.out = out;
    void* kp[] = { (void*)&MA };
    hipError_t err = hipLaunchCooperativeKernel((const void*)k_mega, dim3(coopGrid),
                                                dim3(512), kp, 0, stream);
    if (err == hipSuccess) return;

    // ---- fallback: classic 11-dispatch path
    hipMemsetAsync(deg, 0, 365056, stream);
    k_deg_prepack<<<DEG_NB + PP_NB, 256, 0, stream>>>(dst, deg, W1, W2, D3,
                                                      W1p, W2p, D3p);
    k_scan_local<<<SCAN_NB, 256, 0, stream>>>(deg, rowptr, bsum, dinv, N_NODES);
    k_scanadd<<<SCAN_NB, 256, 0, stream>>>(rowptr, bsum, N_NODES);
    k_fill_xs<<<DEG_NB + CV_NB, 256, 0, stream>>>(src, dst, rowptr, fill, col,
                                                  x, dinv, xs);
    k_layer1<<<ceil_div(N_NODES, 64), 512, 0, stream>>>(xs, rowptr, col, dinv,
                                                        W1p, b1, h1s, N_NODES);
    k_gather2<<<N_NODES / 4, 512, 0, stream>>>(h1s, rowptr, col, dinv, g2);
    {
        dim3 grid(F_H / 64, ceil_div(N_NODES, 128));
        k_gemm_pool<<<grid, 256, 0, stream>>>(g2, W2p, b2, batch, hg, N_NODES);
    }
    k_head_dec<<<N_GRAPHS, 256, 0, stream>>>(hg, batch, Wmu, bmu, Wlv, blv, eps,
                                             D1, db1, D2, db2, out, d2b);
    {
        dim3 grid(P_PAD / 64, ceil_div(N_GRAPHS, 128));
        k_gemm<F_H, 3><<<grid, 256, 0, stream>>>(d2b, D3p, probs, db3,
                                                 N_GRAPHS, P_PAIRS, P_PAD);
    }
    k_adj<<<ceil_div(N_GRAPHS * MAXN * (MAXN / 4), 256), 256, 0, stream>>>(probs, out);
}

// Round 4
// 281.296 us; speedup vs baseline: 3.3582x; 3.3582x over previous
//
#include <hip/hip_runtime.h>
#include <math.h>

#define N_NODES  20000
#define N_EDGES  320000
#define N_GRAPHS 200
#define MAXN     100
#define F_IN     128
#define F_H      256
#define F_L      64
#define P_PAIRS  4950
#define P_PAD    4992                       // P_PAIRS padded to multiple of 64
#define ADJ_SIZE (N_GRAPHS * MAXN * MAXN)   // 2,000,000
#define MU_OFF   ADJ_SIZE
#define LV_OFF   (ADJ_SIZE + N_GRAPHS * F_L)

#define DEG_NB   ((N_EDGES + 255) / 256)    // 1250 blocks

static inline int ceil_div(int a, int b) { return (a + b - 1) / b; }

typedef __attribute__((ext_vector_type(8))) short bf16x8;   // 4 VGPRs
typedef __attribute__((ext_vector_type(4))) float f32x4;    // MFMA acc

// fp32 -> bf16 round-to-nearest-even
static __device__ inline unsigned short f2bf(float f) {
    union { float f; unsigned u; } v; v.f = f;
    unsigned r = (v.u + 0x7FFFu + ((v.u >> 16) & 1u)) >> 16;
    return (unsigned short)r;
}
static __device__ inline float bf2f(unsigned short s) {
    union { unsigned u; float f; } v; v.u = (unsigned)s << 16; return v.f;
}
static __device__ inline float4 ubf4(ushort4 u) {
    float4 f;
    f.x = bf2f(u.x); f.y = bf2f(u.y); f.z = bf2f(u.z); f.w = bf2f(u.w);
    return f;
}

// ---------------------------------------------------------------- fused degree histogram + weight prepack
// Blocks [0, DEG_NB): degree atomics. Blocks [DEG_NB, ...): prepack W1/W2/D3 into
// B-fragment order: Bp[((kt*NT+nt)*64+lane)*8+j] = bf16(W[kt*32+(lane>>4)*8+j][nt*16+(lane&15)])
#define PP_S1  32768                       // W1: 128*256
#define PP_S2  98304                       // + W2: 256*256
#define PP_END 1376256                     // + D3: 256*4992
#define PP_NB  (PP_END / 256)              // 5376
__global__ __launch_bounds__(256) void k_deg_prepack(
        const int* __restrict__ dst, int* __restrict__ deg,
        const float* __restrict__ W1, const float* __restrict__ W2,
        const float* __restrict__ D3,
        unsigned short* __restrict__ W1p, unsigned short* __restrict__ W2p,
        unsigned short* __restrict__ D3p) {
    if (blockIdx.x < DEG_NB) {
        int i = blockIdx.x * 256 + threadIdx.x;
        if (i < N_EDGES) atomicAdd(deg + dst[i], 1);
        return;
    }
    int pid = (blockIdx.x - DEG_NB) * 256 + threadIdx.x;
    const float* W; unsigned short* Bp; int N, NP, t;
    if (pid < PP_S1)      { t = pid;          W = W1; Bp = W1p; N = 256;     NP = 256; }
    else if (pid < PP_S2) { t = pid - PP_S1;  W = W2; Bp = W2p; N = 256;     NP = 256; }
    else if (pid < PP_END){ t = pid - PP_S2;  W = D3; Bp = D3p; N = P_PAIRS; NP = P_PAD; }
    else return;
    int j    = t & 7;
    int lane = (t >> 3) & 63;
    int tile = t >> 9;
    int NT = NP >> 4;
    int nt = tile % NT;
    int kt = tile / NT;
    int k = kt * 32 + (lane >> 4) * 8 + j;
    int n = nt * 16 + (lane & 15);
    Bp[t] = (n < N) ? f2bf(W[(size_t)k * N + n]) : (unsigned short)0;
}

// ---------------------------------------------------------------- single-block scan (+dinv fused)
// One block, 1024 threads, 20 elems/thread; LDS tree over thread totals.
#define SC_PT 20
__global__ __launch_bounds__(1024) void k_scan1(const int* __restrict__ deg,
                                                int* __restrict__ rowptr,
                                                float* __restrict__ dinv) {
    __shared__ int tot[1024];
    const int t = threadIdx.x;
    int loc[SC_PT];
    int base = t * SC_PT;
    int s = 0;
    #pragma unroll
    for (int j = 0; j < SC_PT; ++j) {
        int i = base + j;
        int v = 0;
        if (i < N_NODES) {
            v = deg[i];
            dinv[i] = rsqrtf((float)v + 1.0f);   // +1 self-loop
        }
        s += v;
        loc[j] = s;                              // inclusive within thread
    }
    tot[t] = s;
    __syncthreads();
    // Hillis-Steele inclusive scan over 1024 thread totals
    #pragma unroll
    for (int off = 1; off < 1024; off <<= 1) {
        int v = (t >= off) ? tot[t - off] : 0;
        __syncthreads();
        tot[t] += v;
        __syncthreads();
    }
    int offv = tot[t] - s;                       // exclusive prefix for this thread
    #pragma unroll
    for (int j = 0; j < SC_PT; ++j) {
        int i = base + j;
        if (i < N_NODES) rowptr[i + 1] = offv + loc[j];
    }
    if (t == 0) rowptr[0] = 0;
}

// ---------------------------------------------------------------- CSR fill + xs cast + adj zero (tri-range)
// Blocks [0, DEG_NB): CSR fill atomics. [DEG_NB, DEG_NB+CV_NB): xs = bf16(dinv*x).
// [DEG_NB+CV_NB, ...): zero adjacency output (float4).
#define CV_END 640000                      // N_NODES*F_IN/4 float4 elements
#define CV_NB  (CV_END / 256)              // 2500
#define AZ_END 500000                      // ADJ_SIZE/4 float4 elements
#define AZ_NB  ((AZ_END + 255) / 256)      // 1954
__global__ __launch_bounds__(256) void k_fill_xs(const int* __restrict__ src,
                                                 const int* __restrict__ dst,
                                                 const int* __restrict__ rowptr,
                                                 int* __restrict__ fill,
                                                 int* __restrict__ col,
                                                 const float* __restrict__ x,
                                                 const float* __restrict__ dinv,
                                                 unsigned short* __restrict__ xs,
                                                 float* __restrict__ adj) {
    if (blockIdx.x < DEG_NB) {
        int e = blockIdx.x * 256 + threadIdx.x;
        if (e >= N_EDGES) return;
        int d = dst[e];
        int pos = rowptr[d] + atomicAdd(fill + d, 1);
        col[pos] = src[e];
        return;
    }
    if (blockIdx.x < DEG_NB + CV_NB) {
        int tid = (blockIdx.x - DEG_NB) * 256 + threadIdx.x;
        if (tid >= CV_END) return;
        int v = tid >> 5;                  // 32 float4 per row of 128
        float dv = dinv[v];
        float4 val = ((const float4*)x)[tid];
        ushort4 o;
        o.x = f2bf(val.x * dv); o.y = f2bf(val.y * dv);
        o.z = f2bf(val.z * dv); o.w = f2bf(val.w * dv);
        ((ushort4*)xs)[tid] = o;
        return;
    }
    int tid = (blockIdx.x - DEG_NB - CV_NB) * 256 + threadIdx.x;
    if (tid < AZ_END) ((float4*)adj)[tid] = float4{0.f, 0.f, 0.f, 0.f};
}

// ---------------------------------------------------------------- fused layer 1: gather(x) + MFMA
// Block: 64 nodes x 256 outputs, 512 threads = 8 waves.
// Phase 1: each wave aggregates 8 nodes (full edge list) into XOR-swizzled LDS A-tile (bf16).
// Phase 2: wave (rowgrp 0..1, colgrp 0..3) computes 32 rows x 64 cols via MFMA from LDS.
// Epilogue: relu * dinv[m] -> bf16 (h1s, pre-scaled for gather2).
__global__ __launch_bounds__(512) void k_layer1(const unsigned short* __restrict__ xs,
                                                const int* __restrict__ rowptr,
                                                const int* __restrict__ col,
                                                const float* __restrict__ dinv,
                                                const unsigned short* __restrict__ W1p,
                                                const float* __restrict__ bias,
                                                unsigned short* __restrict__ h1s, int M) {
    __shared__ unsigned short At[64 * 128];     // 16 KB, byte-XOR swizzled
    char* Ab = (char*)At;
    const int tid  = threadIdx.x;
    const int lane = tid & 63;
    const int w    = tid >> 6;

    // ---- gather phase: 8 nodes per wave, lanes cover 128 feats as ushort2
    for (int s = 0; s < 8; ++s) {
        int slot = w * 8 + s;
        int v = blockIdx.x * 64 + slot;
        ushort2 ob; ob.x = 0; ob.y = 0;
        if (v < M) {
            int beg = rowptr[v], end = rowptr[v + 1];
            float2 a0 = make_float2(0.f, 0.f), a1 = make_float2(0.f, 0.f);
            int i = beg;
            for (; i + 8 <= end; i += 8) {
                int s0 = col[i + 0], s1 = col[i + 1], s2 = col[i + 2], s3 = col[i + 3];
                int s4 = col[i + 4], s5 = col[i + 5], s6 = col[i + 6], s7 = col[i + 7];
                ushort2 u0 = ((const ushort2*)(xs + (size_t)s0 * F_IN))[lane];
                ushort2 u1 = ((const ushort2*)(xs + (size_t)s1 * F_IN))[lane];
                ushort2 u2 = ((const ushort2*)(xs + (size_t)s2 * F_IN))[lane];
                ushort2 u3 = ((const ushort2*)(xs + (size_t)s3 * F_IN))[lane];
                ushort2 u4 = ((const ushort2*)(xs + (size_t)s4 * F_IN))[lane];
                ushort2 u5 = ((const ushort2*)(xs + (size_t)s5 * F_IN))[lane];
                ushort2 u6 = ((const ushort2*)(xs + (size_t)s6 * F_IN))[lane];
                ushort2 u7 = ((const ushort2*)(xs + (size_t)s7 * F_IN))[lane];
                a0.x += bf2f(u0.x) + bf2f(u2.x) + bf2f(u4.x) + bf2f(u6.x);
                a0.y += bf2f(u0.y) + bf2f(u2.y) + bf2f(u4.y) + bf2f(u6.y);
                a1.x += bf2f(u1.x) + bf2f(u3.x) + bf2f(u5.x) + bf2f(u7.x);
                a1.y += bf2f(u1.y) + bf2f(u3.y) + bf2f(u5.y) + bf2f(u7.y);
            }
            for (; i + 4 <= end; i += 4) {
                int s0 = col[i + 0], s1 = col[i + 1], s2 = col[i + 2], s3 = col[i + 3];
                ushort2 u0 = ((const ushort2*)(xs + (size_t)s0 * F_IN))[lane];
                ushort2 u1 = ((const ushort2*)(xs + (size_t)s1 * F_IN))[lane];
                ushort2 u2 = ((const ushort2*)(xs + (size_t)s2 * F_IN))[lane];
                ushort2 u3 = ((const ushort2*)(xs + (size_t)s3 * F_IN))[lane];
                a0.x += bf2f(u0.x) + bf2f(u2.x); a0.y += bf2f(u0.y) + bf2f(u2.y);
                a1.x += bf2f(u1.x) + bf2f(u3.x); a1.y += bf2f(u1.y) + bf2f(u3.y);
            }
            for (; i < end; ++i) {
                int sv = col[i];
                ushort2 u = ((const ushort2*)(xs + (size_t)sv * F_IN))[lane];
                a0.x += bf2f(u.x); a0.y += bf2f(u.y);
            }
            ushort2 uv = ((const ushort2*)(xs + (size_t)v * F_IN))[lane];
            float dv = dinv[v];
            ob.x = f2bf(dv * (a0.x + a1.x + bf2f(uv.x)));
            ob.y = f2bf(dv * (a0.y + a1.y + bf2f(uv.y)));
        }
        int byteoff = (slot * 256 + lane * 4) ^ ((slot & 7) << 4);
        *(ushort2*)(Ab + byteoff) = ob;
    }
    __syncthreads();

    // ---- GEMM phase
    const int rowgrp = w >> 2;      // 0..1
    const int colgrp = w & 3;       // 0..3
    const int quad = lane >> 4;
    const int l15  = lane & 15;
    const int r0 = rowgrp * 32 + l15;
    const int r1 = r0 + 16;

    f32x4 acc[2][4];
    #pragma unroll
    for (int i = 0; i < 2; ++i)
        #pragma unroll
        for (int nt = 0; nt < 4; ++nt) acc[i][nt] = (f32x4){0.f, 0.f, 0.f, 0.f};

    #pragma unroll
    for (int kt = 0; kt < 4; ++kt) {
        int c = kt * 64 + quad * 16;
        bf16x8 a0 = *(const bf16x8*)(Ab + ((r0 * 256 + c) ^ ((r0 & 7) << 4)));
        bf16x8 a1 = *(const bf16x8*)(Ab + ((r1 * 256 + c) ^ ((r1 & 7) << 4)));
        #pragma unroll
        for (int nt = 0; nt < 4; ++nt) {
            bf16x8 b = *(const bf16x8*)(W1p + (((size_t)kt * 16 + colgrp * 4 + nt) * 64 + lane) * 8);
            acc[0][nt] = __builtin_amdgcn_mfma_f32_16x16x32_bf16(a0, b, acc[0][nt], 0, 0, 0);
            acc[1][nt] = __builtin_amdgcn_mfma_f32_16x16x32_bf16(a1, b, acc[1][nt], 0, 0, 0);
        }
    }

    // C/D layout: col = lane&15, row = quad*4 + reg
    #pragma unroll
    for (int i = 0; i < 2; ++i) {
        #pragma unroll
        for (int r = 0; r < 4; ++r) {
            int gm = blockIdx.x * 64 + rowgrp * 32 + i * 16 + quad * 4 + r;
            if (gm >= M) continue;
            float dv = dinv[gm];
            #pragma unroll
            for (int nt = 0; nt < 4; ++nt) {
                int gn = colgrp * 64 + nt * 16 + l15;
                float s = acc[i][nt][r] + bias[gn];
                h1s[(size_t)gm * F_H + gn] = f2bf(fmaxf(s, 0.0f) * dv);
            }
        }
    }
}

// ---------------------------------------------------------------- layer-2 GEMM + fused mean-pool sums
__global__ __launch_bounds__(256) void k_gemm_pool(const unsigned short* __restrict__ A,
                                                   const unsigned short* __restrict__ Bp,
                                                   const float* __restrict__ bias,
                                                   const int* __restrict__ batch,
                                                   float* __restrict__ hg, int M) {
    constexpr int KT = F_H / 32;        // 8
    const int NT   = F_H >> 4;          // 16
    const int lane = threadIdx.x & 63;
    const int wave = threadIdx.x >> 6;
    const int bm   = blockIdx.y * 128 + wave * 32;
    const int ng0  = blockIdx.x * 4;
    const int quad = lane >> 4;
    const int l15  = lane & 15;

    __shared__ float sm[128][68];       // stride 68: store pattern 2-way (free)
    __shared__ int gb[128];
    if (threadIdx.x < 128) {
        int gm = blockIdx.y * 128 + threadIdx.x;
        gb[threadIdx.x] = (gm < M) ? batch[gm] : -1;
    }

    int m0 = bm + l15;
    int m1 = m0 + 16;
    int m0c = min(m0, M - 1), m1c = min(m1, M - 1);

    f32x4 acc[2][4];
    #pragma unroll
    for (int i = 0; i < 2; ++i)
        #pragma unroll
        for (int nt = 0; nt < 4; ++nt) acc[i][nt] = (f32x4){0.f, 0.f, 0.f, 0.f};

    #pragma unroll
    for (int kt = 0; kt < KT; ++kt) {
        bf16x8 a0 = *(const bf16x8*)(A + (size_t)m0c * F_H + kt * 32 + quad * 8);
        bf16x8 a1 = *(const bf16x8*)(A + (size_t)m1c * F_H + kt * 32 + quad * 8);
        #pragma unroll
        for (int nt = 0; nt < 4; ++nt) {
            bf16x8 b = *(const bf16x8*)(Bp + (((size_t)kt * NT + ng0 + nt) * 64 + lane) * 8);
            acc[0][nt] = __builtin_amdgcn_mfma_f32_16x16x32_bf16(a0, b, acc[0][nt], 0, 0, 0);
            acc[1][nt] = __builtin_amdgcn_mfma_f32_16x16x32_bf16(a1, b, acc[1][nt], 0, 0, 0);
        }
    }

    // relu + stage to LDS (rows >= M hold garbage; gated by gb == -1 below)
    #pragma unroll
    for (int i = 0; i < 2; ++i) {
        #pragma unroll
        for (int r = 0; r < 4; ++r) {
            int wrow = wave * 32 + i * 16 + quad * 4 + r;
            #pragma unroll
            for (int nt = 0; nt < 4; ++nt) {
                int gn = ((ng0 + nt) << 4) + l15;
                sm[wrow][nt * 16 + l15] = fmaxf(acc[i][nt][r] + bias[gn], 0.0f);
            }
        }
    }
    __syncthreads();

    // segmented per-graph reduction over this block's 128 rows
    int c  = threadIdx.x & 63;
    int r0 = (threadIdx.x >> 6) * 32;
    int gcol = blockIdx.x * 64 + c;
    float s = 0.0f;
    int cur = gb[r0];
    #pragma unroll 4
    for (int r = 0; r < 32; ++r) {
        int g = gb[r0 + r];
        if (g != cur) {
            if (cur >= 0) atomicAdd(hg + (size_t)cur * F_H + gcol, s);
            s = 0.0f; cur = g;
        }
        s += sm[r0 + r][c];
    }
    if (cur >= 0) atomicAdd(hg + (size_t)cur * F_H + gcol, s);
}

// ---------------------------------------------------------------- gather layer 2 (256 feats)
// 512 threads = 8 waves; 2 waves per node (edge-list halves), LDS combine. 8-deep unroll.
__global__ __launch_bounds__(512) void k_gather2(const unsigned short* __restrict__ Hs,
                                                 const int* __restrict__ rowptr,
                                                 const int* __restrict__ col,
                                                 const float* __restrict__ dinv,
                                                 unsigned short* __restrict__ outp) {
    __shared__ float4 part[4][64];
    int w = threadIdx.x >> 6;
    int nl = w >> 1;
    int half = w & 1;
    int v = blockIdx.x * 4 + nl;
    int lane = threadIdx.x & 63;
    int beg = rowptr[v], end = rowptr[v + 1];
    int mid = beg + ((end - beg) >> 1);
    int lo = half ? mid : beg;
    int hi = half ? end : mid;
    float4 a0 = make_float4(0.f, 0.f, 0.f, 0.f);
    float4 a1 = make_float4(0.f, 0.f, 0.f, 0.f);
    int i = lo;
    for (; i + 8 <= hi; i += 8) {
        int s0 = col[i + 0], s1 = col[i + 1], s2 = col[i + 2], s3 = col[i + 3];
        int s4 = col[i + 4], s5 = col[i + 5], s6 = col[i + 6], s7 = col[i + 7];
        float4 h0 = ubf4(((const ushort4*)(Hs + (size_t)s0 * F_H))[lane]);
        float4 h1 = ubf4(((const ushort4*)(Hs + (size_t)s1 * F_H))[lane]);
        float4 h2 = ubf4(((const ushort4*)(Hs + (size_t)s2 * F_H))[lane]);
        float4 h3 = ubf4(((const ushort4*)(Hs + (size_t)s3 * F_H))[lane]);
        float4 h4 = ubf4(((const ushort4*)(Hs + (size_t)s4 * F_H))[lane]);
        float4 h5 = ubf4(((const ushort4*)(Hs + (size_t)s5 * F_H))[lane]);
        float4 h6 = ubf4(((const ushort4*)(Hs + (size_t)s6 * F_H))[lane]);
        float4 h7 = ubf4(((const ushort4*)(Hs + (size_t)s7 * F_H))[lane]);
        a0.x += h0.x + h2.x + h4.x + h6.x; a0.y += h0.y + h2.y + h4.y + h6.y;
        a0.z += h0.z + h2.z + h4.z + h6.z; a0.w += h0.w + h2.w + h4.w + h6.w;
        a1.x += h1.x + h3.x + h5.x + h7.x; a1.y += h1.y + h3.y + h5.y + h7.y;
        a1.z += h1.z + h3.z + h5.z + h7.z; a1.w += h1.w + h3.w + h5.w + h7.w;
    }
    for (; i + 4 <= hi; i += 4) {
        int s0 = col[i + 0], s1 = col[i + 1], s2 = col[i + 2], s3 = col[i + 3];
        float4 h0 = ubf4(((const ushort4*)(Hs + (size_t)s0 * F_H))[lane]);
        float4 h1 = ubf4(((const ushort4*)(Hs + (size_t)s1 * F_H))[lane]);
        float4 h2 = ubf4(((const ushort4*)(Hs + (size_t)s2 * F_H))[lane]);
        float4 h3 = ubf4(((const ushort4*)(Hs + (size_t)s3 * F_H))[lane]);
        a0.x += h0.x + h2.x; a0.y += h0.y + h2.y; a0.z += h0.z + h2.z; a0.w += h0.w + h2.w;
        a1.x += h1.x + h3.x; a1.y += h1.y + h3.y; a1.z += h1.z + h3.z; a1.w += h1.w + h3.w;
    }
    for (; i < hi; ++i) {
        int s = col[i];
        float4 h = ubf4(((const ushort4*)(Hs + (size_t)s * F_H))[lane]);
        a0.x += h.x; a0.y += h.y; a0.z += h.z; a0.w += h.w;
    }
    if (half) part[nl][lane] = make_float4(a0.x + a1.x, a0.y + a1.y,
                                           a0.z + a1.z, a0.w + a1.w);
    __syncthreads();
    if (!half) {
        float4 p = part[nl][lane];
        float dv = dinv[v];
        float4 hv = ubf4(((const ushort4*)(Hs + (size_t)v * F_H))[lane]);
        float ox = dv * (a0.x + a1.x + p.x + hv.x);
        float oy = dv * (a0.y + a1.y + p.y + hv.y);
        float oz = dv * (a0.z + a1.z + p.z + hv.z);
        float ow = dv * (a0.w + a1.w + p.w + hv.w);
        ushort4 ob;
        ob.x = f2bf(ox); ob.y = f2bf(oy); ob.z = f2bf(oz); ob.w = f2bf(ow);
        ((ushort4*)outp)[(size_t)v * 64 + lane] = ob;
    }
}

// ---------------------------------------------------------------- fused head + dec1 + dec2
// hg holds per-graph SUMS (from k_gemm_pool); divide by count via binary search.
__global__ __launch_bounds__(256) void k_head_dec(const float* __restrict__ hg,
                                                  const int* __restrict__ batch,
                                                  const float* __restrict__ Wmu,
                                                  const float* __restrict__ bmu,
                                                  const float* __restrict__ Wlv,
                                                  const float* __restrict__ blv,
                                                  const float* __restrict__ eps,
                                                  const float* __restrict__ D1,
                                                  const float* __restrict__ db1,
                                                  const float* __restrict__ D2,
                                                  const float* __restrict__ db2,
                                                  float* __restrict__ out,
                                                  unsigned short* __restrict__ d2b) {
    int g = blockIdx.x;
    int tid = threadIdx.x;
    __shared__ float hgs[F_H];
    __shared__ float pp[256];
    __shared__ float mulv[128];
    __shared__ float zs[F_L];
    __shared__ float d1s[F_H];
    __shared__ float sInv;
    if (tid == 0) {
        int lo = 0, hi = N_NODES;
        while (lo < hi) { int mid = (lo + hi) >> 1; if (batch[mid] < g) lo = mid + 1; else hi = mid; }
        int beg = lo;
        hi = N_NODES;
        while (lo < hi) { int mid = (lo + hi) >> 1; if (batch[mid] < g + 1) lo = mid + 1; else hi = mid; }
        sInv = 1.0f / fmaxf((float)(lo - beg), 1.0f);
    }
    __syncthreads();
    hgs[tid] = hg[(size_t)g * F_H + tid] * sInv;
    __syncthreads();
    {   // mu/lv: 128 outputs x 2 K-halves
        int o    = tid & 127;          // 0..63 mu, 64..127 lv
        int half = tid >> 7;           // K half
        int l = o & 63;
        const float* W = (o < 64) ? Wmu : Wlv;
        float s = 0.0f;
        int k0 = half * 128;
        #pragma unroll 8
        for (int k = k0; k < k0 + 128; ++k) s += hgs[k] * W[(size_t)k * F_L + l];
        pp[tid] = s;
    }
    __syncthreads();
    if (tid < 128) {
        int l = tid & 63;
        float s = pp[tid] + pp[tid + 128] + ((tid < 64) ? bmu[l] : blv[l]);
        out[((tid < 64) ? MU_OFF : LV_OFF) + g * F_L + l] = s;
        mulv[tid] = s;
    }
    __syncthreads();
    if (tid < 64)
        zs[tid] = mulv[tid] + eps[g * F_L + tid] * expf(0.5f * mulv[64 + tid]);
    __syncthreads();
    {   // d1 = relu(z @ D1 + db1): K=64
        float s = db1[tid];
        #pragma unroll 8
        for (int k = 0; k < F_L; ++k) s += zs[k] * D1[(size_t)k * F_H + tid];
        d1s[tid] = fmaxf(s, 0.0f);
    }
    __syncthreads();
    {   // d2 = relu(d1 @ D2 + db2): K=256
        float s = db2[tid];
        #pragma unroll 8
        for (int k = 0; k < F_H; ++k) s += d1s[k] * D2[(size_t)k * F_H + tid];
        d2b[(size_t)g * F_H + tid] = f2bf(fmaxf(s, 0.0f));
    }
}

// ---------------------------------------------------------------- decoder D3 GEMM + fused adjacency scatter
// Block: 128 rows x 64 cols (4 waves); writes sigmoid directly into both triangles of adj.
// adj pre-zeroed (k_fill_xs third range); diagonal stays zero.
__global__ __launch_bounds__(256) void k_d3adj(const unsigned short* __restrict__ A,
                                               const unsigned short* __restrict__ Bp,
                                               const float* __restrict__ db3,
                                               float* __restrict__ adj) {
    constexpr int KT = F_H / 32;        // 8
    constexpr int NT = P_PAD >> 4;      // 312
    const int lane = threadIdx.x & 63;
    const int wave = threadIdx.x >> 6;
    const int bm   = blockIdx.y * 128 + wave * 32;
    const int ng0  = blockIdx.x * 4;
    const int quad = lane >> 4;
    const int l15  = lane & 15;

    int m0 = bm + l15;
    int m1 = m0 + 16;
    int m0c = min(m0, N_GRAPHS - 1), m1c = min(m1, N_GRAPHS - 1);

    f32x4 acc[2][4];
    #pragma unroll
    for (int i = 0; i < 2; ++i)
        #pragma unroll
        for (int nt = 0; nt < 4; ++nt) acc[i][nt] = (f32x4){0.f, 0.f, 0.f, 0.f};

    #pragma unroll
    for (int kt = 0; kt < KT; ++kt) {
        bf16x8 a0 = *(const bf16x8*)(A + (size_t)m0c * F_H + kt * 32 + quad * 8);
        bf16x8 a1 = *(const bf16x8*)(A + (size_t)m1c * F_H + kt * 32 + quad * 8);
        #pragma unroll
        for (int nt = 0; nt < 4; ++nt) {
            bf16x8 b = *(const bf16x8*)(Bp + (((size_t)kt * NT + ng0 + nt) * 64 + lane) * 8);
            acc[0][nt] = __builtin_amdgcn_mfma_f32_16x16x32_bf16(a0, b, acc[0][nt], 0, 0, 0);
            acc[1][nt] = __builtin_amdgcn_mfma_f32_16x16x32_bf16(a1, b, acc[1][nt], 0, 0, 0);
        }
    }

    // decode pair index p=gn -> (a,b), upper triangle (verified in-mega, passed)
    int aa[4], bb[4], gn_[4]; float bias_[4];
    #pragma unroll
    for (int j = 0; j < 4; ++j) {
        int gn = (ng0 + j) * 16 + l15;
        gn_[j] = gn;
        int p = (gn < P_PAIRS) ? gn : 0;
        bias_[j] = (gn < P_PAIRS) ? db3[gn] : 0.0f;
        int a = (int)floorf((199.0f - sqrtf((float)(39601 - 8 * p))) * 0.5f);
        if (a < 0) a = 0;
        while (a * (199 - a) / 2 > p) --a;
        while ((a + 1) * (198 - a) / 2 <= p) ++a;
        aa[j] = a;
        bb[j] = p - a * (199 - a) / 2 + a + 1;
    }

    // C/D layout: col = lane&15, row = quad*4 + reg
    #pragma unroll
    for (int i = 0; i < 2; ++i) {
        #pragma unroll
        for (int r = 0; r < 4; ++r) {
            int gm = bm + i * 16 + quad * 4 + r;
            if (gm >= N_GRAPHS) continue;
            float* og = adj + (size_t)gm * (MAXN * MAXN);
            #pragma unroll
            for (int j = 0; j < 4; ++j) {
                if (gn_[j] < P_PAIRS) {
                    float s = acc[i][j][r] + bias_[j];
                    float pr = 1.0f / (1.0f + expf(-s));
                    og[aa[j] * MAXN + bb[j]] = pr;
                    og[bb[j] * MAXN + aa[j]] = pr;
                }
            }
        }
    }
}

// ================================================================ launch
extern "C" void kernel_launch(void* const* d_in, const int* in_sizes, int n_in,
                              void* d_out, int out_size, void* d_ws, size_t ws_size,
                              hipStream_t stream) {
    const float* x    = (const float*)d_in[0];
    const int*   eidx = (const int*)d_in[1];
    const int*   batch= (const int*)d_in[2];
    const float* eps  = (const float*)d_in[3];
    const float* W1   = (const float*)d_in[4];
    const float* b1   = (const float*)d_in[5];
    const float* W2   = (const float*)d_in[6];
    const float* b2   = (const float*)d_in[7];
    const float* Wmu  = (const float*)d_in[8];
    const float* bmu  = (const float*)d_in[9];
    const float* Wlv  = (const float*)d_in[10];
    const float* blv  = (const float*)d_in[11];
    const float* D1   = (const float*)d_in[12];
    const float* db1  = (const float*)d_in[13];
    const float* D2   = (const float*)d_in[14];
    const float* db2  = (const float*)d_in[15];
    const float* D3   = (const float*)d_in[16];
    const float* db3  = (const float*)d_in[17];

    const int* src = eidx;
    const int* dst = eidx + N_EDGES;
    float* out = (float*)d_out;

    // workspace carve-up (deg, fill, hg contiguous -> single memset)
    char* wsb = (char*)d_ws;
    size_t o = 0;
    auto carve = [&](size_t bytes) { void* p = wsb + o; o += (bytes + 255) & ~255ull; return p; };
    int*   deg    = (int*)  carve(N_NODES * sizeof(int));              // 80128
    int*   fill   = (int*)  carve(N_NODES * sizeof(int));              // 80128
    float* hg     = (float*)carve((size_t)N_GRAPHS * F_H * sizeof(float)); // 204800
    int*   rowptr = (int*)  carve((N_NODES + 1) * sizeof(int));
    int*   col    = (int*)  carve(N_EDGES * sizeof(int));
    float* dinv   = (float*)carve(N_NODES * sizeof(float));
    unsigned short* xs  = (unsigned short*)carve((size_t)N_NODES * F_IN * sizeof(short));
    unsigned short* W1p = (unsigned short*)carve((size_t)F_IN * F_H * sizeof(short));
    unsigned short* W2p = (unsigned short*)carve((size_t)F_H * F_H * sizeof(short));
    unsigned short* D3p = (unsigned short*)carve((size_t)F_H * P_PAD * sizeof(short));
    unsigned short* h1s = (unsigned short*)carve((size_t)N_NODES * F_H * sizeof(short));  // dinv*h1
    unsigned short* g2  = (unsigned short*)carve((size_t)N_NODES * F_H * sizeof(short));  // agg h1
    unsigned short* d2b = (unsigned short*)carve((size_t)N_GRAPHS * F_H * sizeof(short));

    // ---- CSR build + prepack (deg+fill+hg zeroed in one contiguous memset)
    hipMemsetAsync(deg, 0, 365056, stream);
    k_deg_prepack<<<DEG_NB + PP_NB, 256, 0, stream>>>(dst, deg, W1, W2, D3,
                                                      W1p, W2p, D3p);
    k_scan1<<<1, 1024, 0, stream>>>(deg, rowptr, dinv);
    k_fill_xs<<<DEG_NB + CV_NB + AZ_NB, 256, 0, stream>>>(src, dst, rowptr, fill, col,
                                                          x, dinv, xs, out);

    // ---- GCN layer 1: fused gather(x) + MFMA transform (LDS A-tile)
    k_layer1<<<ceil_div(N_NODES, 64), 512, 0, stream>>>(xs, rowptr, col, dinv,
                                                        W1p, b1, h1s, N_NODES);

    // ---- GCN layer 2: aggregate h1s (256 feats), then MFMA + fused mean-pool sums
    k_gather2<<<N_NODES / 4, 512, 0, stream>>>(h1s, rowptr, col, dinv, g2);
    {
        dim3 grid(F_H / 64, ceil_div(N_NODES, 128));
        k_gemm_pool<<<grid, 256, 0, stream>>>(g2, W2p, b2, batch, hg, N_NODES);
    }

    // ---- head/dec1/dec2 (divides hg sums by per-graph count)
    k_head_dec<<<N_GRAPHS, 256, 0, stream>>>(hg, batch, Wmu, bmu, Wlv, blv, eps,
                                             D1, db1, D2, db2, out, d2b);

    // ---- decoder D3 GEMM + fused adjacency scatter (adj pre-zeroed in k_fill_xs)
    {
        dim3 grid(P_PAD / 64, ceil_div(N_GRAPHS, 128));
        k_d3adj<<<grid, 256, 0, stream>>>(d2b, D3p, db3, out);
    }
}

// Round 5
// 243.205 us; speedup vs baseline: 3.8841x; 1.1566x over previous
//
#include <hip/hip_runtime.h>
#include <math.h>

#define N_NODES  20000
#define N_EDGES  320000
#define N_GRAPHS 200
#define MAXN     100
#define F_IN     128
#define F_H      256
#define F_L      64
#define P_PAIRS  4950
#define P_PAD    4992                       // P_PAIRS padded to multiple of 64
#define ADJ_SIZE (N_GRAPHS * MAXN * MAXN)   // 2,000,000
#define MU_OFF   ADJ_SIZE
#define LV_OFF   (ADJ_SIZE + N_GRAPHS * F_L)

#define ELL_W    64                         // ELL row capacity (deg ~ Poisson(16); 64 = ~12 sigma)
#define EF_NB    ((N_EDGES + 255) / 256)    // 1250 edge-fill blocks

static inline int ceil_div(int a, int b) { return (a + b - 1) / b; }

typedef __attribute__((ext_vector_type(8))) short bf16x8;   // 4 VGPRs
typedef __attribute__((ext_vector_type(4))) float f32x4;    // MFMA acc

// fp32 -> bf16 round-to-nearest-even
static __device__ inline unsigned short f2bf(float f) {
    union { float f; unsigned u; } v; v.f = f;
    unsigned r = (v.u + 0x7FFFu + ((v.u >> 16) & 1u)) >> 16;
    return (unsigned short)r;
}
static __device__ inline float bf2f(unsigned short s) {
    union { unsigned u; float f; } v; v.u = (unsigned)s << 16; return v.f;
}
static __device__ inline float4 ubf4(ushort4 u) {
    float4 f;
    f.x = bf2f(u.x); f.y = bf2f(u.y); f.z = bf2f(u.z); f.w = bf2f(u.w);
    return f;
}

// ---------------------------------------------------------------- fused ELL fill + weight prepack
// Blocks [0, EF_NB): direct ELL CSR-free fill (fill[] = bump counters = degrees).
// Blocks [EF_NB, ...): prepack W1/W2/D3 into B-fragment order:
// Bp[((kt*NT+nt)*64+lane)*8+j] = bf16(W[kt*32+(lane>>4)*8+j][nt*16+(lane&15)])
#define PP_S1  32768                       // W1: 128*256
#define PP_S2  98304                       // + W2: 256*256
#define PP_END 1376256                     // + D3: 256*4992
#define PP_NB  (PP_END / 256)              // 5376
__global__ __launch_bounds__(256) void k_fill_prepack(
        const int* __restrict__ src, const int* __restrict__ dst,
        int* __restrict__ fill, int* __restrict__ ell,
        const float* __restrict__ W1, const float* __restrict__ W2,
        const float* __restrict__ D3,
        unsigned short* __restrict__ W1p, unsigned short* __restrict__ W2p,
        unsigned short* __restrict__ D3p) {
    if (blockIdx.x < EF_NB) {
        int e = blockIdx.x * 256 + threadIdx.x;
        if (e < N_EDGES) {
            int d = dst[e];
            int pos = atomicAdd(fill + d, 1);
            if (pos < ELL_W) ell[d * ELL_W + pos] = src[e];
        }
        return;
    }
    int pid = (blockIdx.x - EF_NB) * 256 + threadIdx.x;
    const float* W; unsigned short* Bp; int N, NP, t;
    if (pid < PP_S1)      { t = pid;          W = W1; Bp = W1p; N = 256;     NP = 256; }
    else if (pid < PP_S2) { t = pid - PP_S1;  W = W2; Bp = W2p; N = 256;     NP = 256; }
    else if (pid < PP_END){ t = pid - PP_S2;  W = D3; Bp = D3p; N = P_PAIRS; NP = P_PAD; }
    else return;
    int j    = t & 7;
    int lane = (t >> 3) & 63;
    int tile = t >> 9;
    int NT = NP >> 4;
    int nt = tile % NT;
    int kt = tile / NT;
    int k = kt * 32 + (lane >> 4) * 8 + j;
    int n = nt * 16 + (lane & 15);
    Bp[t] = (n < N) ? f2bf(W[(size_t)k * N + n]) : (unsigned short)0;
}

// ---------------------------------------------------------------- dinv + xs cast (dual-range)
// Blocks [0, DV_NB): dinv[i] = rsqrt(deg+1). Blocks [DV_NB, ...): xs = bf16(dinv*x)
// (dinv recomputed inline from fill[] to avoid intra-dispatch dependency).
#define DV_NB  ((N_NODES + 255) / 256)     // 79
#define CV_END 640000                      // N_NODES*F_IN/4 float4 elements
#define CV_NB  (CV_END / 256)              // 2500
__global__ __launch_bounds__(256) void k_dinv_xs(const int* __restrict__ fill,
                                                 float* __restrict__ dinv,
                                                 const float* __restrict__ x,
                                                 unsigned short* __restrict__ xs) {
    if (blockIdx.x < DV_NB) {
        int i = blockIdx.x * 256 + threadIdx.x;
        if (i < N_NODES) dinv[i] = rsqrtf((float)fill[i] + 1.0f);   // +1 self-loop
        return;
    }
    int tid = (blockIdx.x - DV_NB) * 256 + threadIdx.x;
    if (tid >= CV_END) return;
    int v = tid >> 5;                  // 32 float4 per row of 128
    float dv = rsqrtf((float)fill[v] + 1.0f);
    float4 val = ((const float4*)x)[tid];
    ushort4 o;
    o.x = f2bf(val.x * dv); o.y = f2bf(val.y * dv);
    o.z = f2bf(val.z * dv); o.w = f2bf(val.w * dv);
    ((ushort4*)xs)[tid] = o;
}

// ---------------------------------------------------------------- fused layer 1: gather(x) + MFMA
// Block: 64 nodes x 256 outputs, 512 threads = 8 waves.
// Phase 1: each wave aggregates 8 nodes (ELL row) into XOR-swizzled LDS A-tile (bf16).
// Phase 2: wave (rowgrp 0..1, colgrp 0..3) computes 32 rows x 64 cols via MFMA from LDS.
// Epilogue: relu * dinv[m] -> bf16 (h1s, pre-scaled for gather2).
__global__ __launch_bounds__(512) void k_layer1(const unsigned short* __restrict__ xs,
                                                const int* __restrict__ fill,
                                                const int* __restrict__ ell,
                                                const float* __restrict__ dinv,
                                                const unsigned short* __restrict__ W1p,
                                                const float* __restrict__ bias,
                                                unsigned short* __restrict__ h1s, int M) {
    __shared__ unsigned short At[64 * 128];     // 16 KB, byte-XOR swizzled
    char* Ab = (char*)At;
    const int tid  = threadIdx.x;
    const int lane = tid & 63;
    const int w    = tid >> 6;

    // ---- gather phase: 8 nodes per wave, lanes cover 128 feats as ushort2
    for (int s = 0; s < 8; ++s) {
        int slot = w * 8 + s;
        int v = blockIdx.x * 64 + slot;
        ushort2 ob; ob.x = 0; ob.y = 0;
        if (v < M) {
            int beg = v * ELL_W;
            int end = beg + min(fill[v], ELL_W);
            float2 a0 = make_float2(0.f, 0.f), a1 = make_float2(0.f, 0.f);
            int i = beg;
            for (; i + 8 <= end; i += 8) {
                int s0 = ell[i + 0], s1 = ell[i + 1], s2 = ell[i + 2], s3 = ell[i + 3];
                int s4 = ell[i + 4], s5 = ell[i + 5], s6 = ell[i + 6], s7 = ell[i + 7];
                ushort2 u0 = ((const ushort2*)(xs + (size_t)s0 * F_IN))[lane];
                ushort2 u1 = ((const ushort2*)(xs + (size_t)s1 * F_IN))[lane];
                ushort2 u2 = ((const ushort2*)(xs + (size_t)s2 * F_IN))[lane];
                ushort2 u3 = ((const ushort2*)(xs + (size_t)s3 * F_IN))[lane];
                ushort2 u4 = ((const ushort2*)(xs + (size_t)s4 * F_IN))[lane];
                ushort2 u5 = ((const ushort2*)(xs + (size_t)s5 * F_IN))[lane];
                ushort2 u6 = ((const ushort2*)(xs + (size_t)s6 * F_IN))[lane];
                ushort2 u7 = ((const ushort2*)(xs + (size_t)s7 * F_IN))[lane];
                a0.x += bf2f(u0.x) + bf2f(u2.x) + bf2f(u4.x) + bf2f(u6.x);
                a0.y += bf2f(u0.y) + bf2f(u2.y) + bf2f(u4.y) + bf2f(u6.y);
                a1.x += bf2f(u1.x) + bf2f(u3.x) + bf2f(u5.x) + bf2f(u7.x);
                a1.y += bf2f(u1.y) + bf2f(u3.y) + bf2f(u5.y) + bf2f(u7.y);
            }
            for (; i + 4 <= end; i += 4) {
                int s0 = ell[i + 0], s1 = ell[i + 1], s2 = ell[i + 2], s3 = ell[i + 3];
                ushort2 u0 = ((const ushort2*)(xs + (size_t)s0 * F_IN))[lane];
                ushort2 u1 = ((const ushort2*)(xs + (size_t)s1 * F_IN))[lane];
                ushort2 u2 = ((const ushort2*)(xs + (size_t)s2 * F_IN))[lane];
                ushort2 u3 = ((const ushort2*)(xs + (size_t)s3 * F_IN))[lane];
                a0.x += bf2f(u0.x) + bf2f(u2.x); a0.y += bf2f(u0.y) + bf2f(u2.y);
                a1.x += bf2f(u1.x) + bf2f(u3.x); a1.y += bf2f(u1.y) + bf2f(u3.y);
            }
            for (; i < end; ++i) {
                int sv = ell[i];
                ushort2 u = ((const ushort2*)(xs + (size_t)sv * F_IN))[lane];
                a0.x += bf2f(u.x); a0.y += bf2f(u.y);
            }
            ushort2 uv = ((const ushort2*)(xs + (size_t)v * F_IN))[lane];
            float dv = dinv[v];
            ob.x = f2bf(dv * (a0.x + a1.x + bf2f(uv.x)));
            ob.y = f2bf(dv * (a0.y + a1.y + bf2f(uv.y)));
        }
        int byteoff = (slot * 256 + lane * 4) ^ ((slot & 7) << 4);
        *(ushort2*)(Ab + byteoff) = ob;
    }
    __syncthreads();

    // ---- GEMM phase
    const int rowgrp = w >> 2;      // 0..1
    const int colgrp = w & 3;       // 0..3
    const int quad = lane >> 4;
    const int l15  = lane & 15;
    const int r0 = rowgrp * 32 + l15;
    const int r1 = r0 + 16;

    f32x4 acc[2][4];
    #pragma unroll
    for (int i = 0; i < 2; ++i)
        #pragma unroll
        for (int nt = 0; nt < 4; ++nt) acc[i][nt] = (f32x4){0.f, 0.f, 0.f, 0.f};

    #pragma unroll
    for (int kt = 0; kt < 4; ++kt) {
        int c = kt * 64 + quad * 16;
        bf16x8 a0 = *(const bf16x8*)(Ab + ((r0 * 256 + c) ^ ((r0 & 7) << 4)));
        bf16x8 a1 = *(const bf16x8*)(Ab + ((r1 * 256 + c) ^ ((r1 & 7) << 4)));
        #pragma unroll
        for (int nt = 0; nt < 4; ++nt) {
            bf16x8 b = *(const bf16x8*)(W1p + (((size_t)kt * 16 + colgrp * 4 + nt) * 64 + lane) * 8);
            acc[0][nt] = __builtin_amdgcn_mfma_f32_16x16x32_bf16(a0, b, acc[0][nt], 0, 0, 0);
            acc[1][nt] = __builtin_amdgcn_mfma_f32_16x16x32_bf16(a1, b, acc[1][nt], 0, 0, 0);
        }
    }

    // C/D layout: col = lane&15, row = quad*4 + reg
    #pragma unroll
    for (int i = 0; i < 2; ++i) {
        #pragma unroll
        for (int r = 0; r < 4; ++r) {
            int gm = blockIdx.x * 64 + rowgrp * 32 + i * 16 + quad * 4 + r;
            if (gm >= M) continue;
            float dv = dinv[gm];
            #pragma unroll
            for (int nt = 0; nt < 4; ++nt) {
                int gn = colgrp * 64 + nt * 16 + l15;
                float s = acc[i][nt][r] + bias[gn];
                h1s[(size_t)gm * F_H + gn] = f2bf(fmaxf(s, 0.0f) * dv);
            }
        }
    }
}

// ---------------------------------------------------------------- layer-2 GEMM + fused mean-pool sums
__global__ __launch_bounds__(256) void k_gemm_pool(const unsigned short* __restrict__ A,
                                                   const unsigned short* __restrict__ Bp,
                                                   const float* __restrict__ bias,
                                                   const int* __restrict__ batch,
                                                   float* __restrict__ hg, int M) {
    constexpr int KT = F_H / 32;        // 8
    const int NT   = F_H >> 4;          // 16
    const int lane = threadIdx.x & 63;
    const int wave = threadIdx.x >> 6;
    const int bm   = blockIdx.y * 128 + wave * 32;
    const int ng0  = blockIdx.x * 4;
    const int quad = lane >> 4;
    const int l15  = lane & 15;

    __shared__ float sm[128][68];       // stride 68: store pattern 2-way (free)
    __shared__ int gb[128];
    if (threadIdx.x < 128) {
        int gm = blockIdx.y * 128 + threadIdx.x;
        gb[threadIdx.x] = (gm < M) ? batch[gm] : -1;
    }

    int m0 = bm + l15;
    int m1 = m0 + 16;
    int m0c = min(m0, M - 1), m1c = min(m1, M - 1);

    f32x4 acc[2][4];
    #pragma unroll
    for (int i = 0; i < 2; ++i)
        #pragma unroll
        for (int nt = 0; nt < 4; ++nt) acc[i][nt] = (f32x4){0.f, 0.f, 0.f, 0.f};

    #pragma unroll
    for (int kt = 0; kt < KT; ++kt) {
        bf16x8 a0 = *(const bf16x8*)(A + (size_t)m0c * F_H + kt * 32 + quad * 8);
        bf16x8 a1 = *(const bf16x8*)(A + (size_t)m1c * F_H + kt * 32 + quad * 8);
        #pragma unroll
        for (int nt = 0; nt < 4; ++nt) {
            bf16x8 b = *(const bf16x8*)(Bp + (((size_t)kt * NT + ng0 + nt) * 64 + lane) * 8);
            acc[0][nt] = __builtin_amdgcn_mfma_f32_16x16x32_bf16(a0, b, acc[0][nt], 0, 0, 0);
            acc[1][nt] = __builtin_amdgcn_mfma_f32_16x16x32_bf16(a1, b, acc[1][nt], 0, 0, 0);
        }
    }

    // relu + stage to LDS (rows >= M hold garbage; gated by gb == -1 below)
    #pragma unroll
    for (int i = 0; i < 2; ++i) {
        #pragma unroll
        for (int r = 0; r < 4; ++r) {
            int wrow = wave * 32 + i * 16 + quad * 4 + r;
            #pragma unroll
            for (int nt = 0; nt < 4; ++nt) {
                int gn = ((ng0 + nt) << 4) + l15;
                sm[wrow][nt * 16 + l15] = fmaxf(acc[i][nt][r] + bias[gn], 0.0f);
            }
        }
    }
    __syncthreads();

    // segmented per-graph reduction over this block's 128 rows
    int c  = threadIdx.x & 63;
    int r0 = (threadIdx.x >> 6) * 32;
    int gcol = blockIdx.x * 64 + c;
    float s = 0.0f;
    int cur = gb[r0];
    #pragma unroll 4
    for (int r = 0; r < 32; ++r) {
        int g = gb[r0 + r];
        if (g != cur) {
            if (cur >= 0) atomicAdd(hg + (size_t)cur * F_H + gcol, s);
            s = 0.0f; cur = g;
        }
        s += sm[r0 + r][c];
    }
    if (cur >= 0) atomicAdd(hg + (size_t)cur * F_H + gcol, s);
}

// ---------------------------------------------------------------- gather layer 2 (256 feats)
// 512 threads = 8 waves; 2 waves per node (ELL row halves), LDS combine. 8-deep unroll.
__global__ __launch_bounds__(512) void k_gather2(const unsigned short* __restrict__ Hs,
                                                 const int* __restrict__ fill,
                                                 const int* __restrict__ ell,
                                                 const float* __restrict__ dinv,
                                                 unsigned short* __restrict__ outp) {
    __shared__ float4 part[4][64];
    int w = threadIdx.x >> 6;
    int nl = w >> 1;
    int half = w & 1;
    int v = blockIdx.x * 4 + nl;
    int lane = threadIdx.x & 63;
    int beg = v * ELL_W;
    int end = beg + min(fill[v], ELL_W);
    int mid = beg + ((end - beg) >> 1);
    int lo = half ? mid : beg;
    int hi = half ? end : mid;
    float4 a0 = make_float4(0.f, 0.f, 0.f, 0.f);
    float4 a1 = make_float4(0.f, 0.f, 0.f, 0.f);
    int i = lo;
    for (; i + 8 <= hi; i += 8) {
        int s0 = ell[i + 0], s1 = ell[i + 1], s2 = ell[i + 2], s3 = ell[i + 3];
        int s4 = ell[i + 4], s5 = ell[i + 5], s6 = ell[i + 6], s7 = ell[i + 7];
        float4 h0 = ubf4(((const ushort4*)(Hs + (size_t)s0 * F_H))[lane]);
        float4 h1 = ubf4(((const ushort4*)(Hs + (size_t)s1 * F_H))[lane]);
        float4 h2 = ubf4(((const ushort4*)(Hs + (size_t)s2 * F_H))[lane]);
        float4 h3 = ubf4(((const ushort4*)(Hs + (size_t)s3 * F_H))[lane]);
        float4 h4 = ubf4(((const ushort4*)(Hs + (size_t)s4 * F_H))[lane]);
        float4 h5 = ubf4(((const ushort4*)(Hs + (size_t)s5 * F_H))[lane]);
        float4 h6 = ubf4(((const ushort4*)(Hs + (size_t)s6 * F_H))[lane]);
        float4 h7 = ubf4(((const ushort4*)(Hs + (size_t)s7 * F_H))[lane]);
        a0.x += h0.x + h2.x + h4.x + h6.x; a0.y += h0.y + h2.y + h4.y + h6.y;
        a0.z += h0.z + h2.z + h4.z + h6.z; a0.w += h0.w + h2.w + h4.w + h6.w;
        a1.x += h1.x + h3.x + h5.x + h7.x; a1.y += h1.y + h3.y + h5.y + h7.y;
        a1.z += h1.z + h3.z + h5.z + h7.z; a1.w += h1.w + h3.w + h5.w + h7.w;
    }
    for (; i + 4 <= hi; i += 4) {
        int s0 = ell[i + 0], s1 = ell[i + 1], s2 = ell[i + 2], s3 = ell[i + 3];
        float4 h0 = ubf4(((const ushort4*)(Hs + (size_t)s0 * F_H))[lane]);
        float4 h1 = ubf4(((const ushort4*)(Hs + (size_t)s1 * F_H))[lane]);
        float4 h2 = ubf4(((const ushort4*)(Hs + (size_t)s2 * F_H))[lane]);
        float4 h3 = ubf4(((const ushort4*)(Hs + (size_t)s3 * F_H))[lane]);
        a0.x += h0.x + h2.x; a0.y += h0.y + h2.y; a0.z += h0.z + h2.z; a0.w += h0.w + h2.w;
        a1.x += h1.x + h3.x; a1.y += h1.y + h3.y; a1.z += h1.z + h3.z; a1.w += h1.w + h3.w;
    }
    for (; i < hi; ++i) {
        int s = ell[i];
        float4 h = ubf4(((const ushort4*)(Hs + (size_t)s * F_H))[lane]);
        a0.x += h.x; a0.y += h.y; a0.z += h.z; a0.w += h.w;
    }
    if (half) part[nl][lane] = make_float4(a0.x + a1.x, a0.y + a1.y,
                                           a0.z + a1.z, a0.w + a1.w);
    __syncthreads();
    if (!half) {
        float4 p = part[nl][lane];
        float dv = dinv[v];
        float4 hv = ubf4(((const ushort4*)(Hs + (size_t)v * F_H))[lane]);
        float ox = dv * (a0.x + a1.x + p.x + hv.x);
        float oy = dv * (a0.y + a1.y + p.y + hv.y);
        float oz = dv * (a0.z + a1.z + p.z + hv.z);
        float ow = dv * (a0.w + a1.w + p.w + hv.w);
        ushort4 ob;
        ob.x = f2bf(ox); ob.y = f2bf(oy); ob.z = f2bf(oz); ob.w = f2bf(ow);
        ((ushort4*)outp)[(size_t)v * 64 + lane] = ob;
    }
}

// ---------------------------------------------------------------- fused head + dec1 + dec2
// hg holds per-graph SUMS (from k_gemm_pool); divide by count via binary search.
__global__ __launch_bounds__(256) void k_head_dec(const float* __restrict__ hg,
                                                  const int* __restrict__ batch,
                                                  const float* __restrict__ Wmu,
                                                  const float* __restrict__ bmu,
                                                  const float* __restrict__ Wlv,
                                                  const float* __restrict__ blv,
                                                  const float* __restrict__ eps,
                                                  const float* __restrict__ D1,
                                                  const float* __restrict__ db1,
                                                  const float* __restrict__ D2,
                                                  const float* __restrict__ db2,
                                                  float* __restrict__ out,
                                                  unsigned short* __restrict__ d2b) {
    int g = blockIdx.x;
    int tid = threadIdx.x;
    __shared__ float hgs[F_H];
    __shared__ float pp[256];
    __shared__ float mulv[128];
    __shared__ float zs[F_L];
    __shared__ float d1s[F_H];
    __shared__ float sInv;
    if (tid == 0) {
        int lo = 0, hi = N_NODES;
        while (lo < hi) { int mid = (lo + hi) >> 1; if (batch[mid] < g) lo = mid + 1; else hi = mid; }
        int beg = lo;
        hi = N_NODES;
        while (lo < hi) { int mid = (lo + hi) >> 1; if (batch[mid] < g + 1) lo = mid + 1; else hi = mid; }
        sInv = 1.0f / fmaxf((float)(lo - beg), 1.0f);
    }
    __syncthreads();
    hgs[tid] = hg[(size_t)g * F_H + tid] * sInv;
    __syncthreads();
    {   // mu/lv: 128 outputs x 2 K-halves
        int o    = tid & 127;          // 0..63 mu, 64..127 lv
        int half = tid >> 7;           // K half
        int l = o & 63;
        const float* W = (o < 64) ? Wmu : Wlv;
        float s = 0.0f;
        int k0 = half * 128;
        #pragma unroll 8
        for (int k = k0; k < k0 + 128; ++k) s += hgs[k] * W[(size_t)k * F_L + l];
        pp[tid] = s;
    }
    __syncthreads();
    if (tid < 128) {
        int l = tid & 63;
        float s = pp[tid] + pp[tid + 128] + ((tid < 64) ? bmu[l] : blv[l]);
        out[((tid < 64) ? MU_OFF : LV_OFF) + g * F_L + l] = s;
        mulv[tid] = s;
    }
    __syncthreads();
    if (tid < 64)
        zs[tid] = mulv[tid] + eps[g * F_L + tid] * expf(0.5f * mulv[64 + tid]);
    __syncthreads();
    {   // d1 = relu(z @ D1 + db1): K=64
        float s = db1[tid];
        #pragma unroll 8
        for (int k = 0; k < F_L; ++k) s += zs[k] * D1[(size_t)k * F_H + tid];
        d1s[tid] = fmaxf(s, 0.0f);
    }
    __syncthreads();
    {   // d2 = relu(d1 @ D2 + db2): K=256
        float s = db2[tid];
        #pragma unroll 8
        for (int k = 0; k < F_H; ++k) s += d1s[k] * D2[(size_t)k * F_H + tid];
        d2b[(size_t)g * F_H + tid] = f2bf(fmaxf(s, 0.0f));
    }
}

// ---------------------------------------------------------------- decoder D3 GEMM (sigmoid -> probs)
__global__ __launch_bounds__(256) void k_gemm3(const unsigned short* __restrict__ A,
                                               const unsigned short* __restrict__ Bp,
                                               float* __restrict__ Y,
                                               const float* __restrict__ bias,
                                               int M, int N, int NP) {
    constexpr int KT = F_H / 32;
    const int NT   = NP >> 4;
    const int lane = threadIdx.x & 63;
    const int wave = threadIdx.x >> 6;
    const int bm   = blockIdx.y * 128 + wave * 32;
    const int ng0  = blockIdx.x * 4;
    const int quad = lane >> 4;
    const int l15  = lane & 15;

    int m0 = bm + l15;
    int m1 = m0 + 16;
    int m0c = min(m0, M - 1), m1c = min(m1, M - 1);

    f32x4 acc[2][4];
    #pragma unroll
    for (int i = 0; i < 2; ++i)
        #pragma unroll
        for (int nt = 0; nt < 4; ++nt) acc[i][nt] = (f32x4){0.f, 0.f, 0.f, 0.f};

    #pragma unroll
    for (int kt = 0; kt < KT; ++kt) {
        bf16x8 a0 = *(const bf16x8*)(A + (size_t)m0c * F_H + kt * 32 + quad * 8);
        bf16x8 a1 = *(const bf16x8*)(A + (size_t)m1c * F_H + kt * 32 + quad * 8);
        #pragma unroll
        for (int nt = 0; nt < 4; ++nt) {
            bf16x8 b = *(const bf16x8*)(Bp + (((size_t)kt * NT + ng0 + nt) * 64 + lane) * 8);
            acc[0][nt] = __builtin_amdgcn_mfma_f32_16x16x32_bf16(a0, b, acc[0][nt], 0, 0, 0);
            acc[1][nt] = __builtin_amdgcn_mfma_f32_16x16x32_bf16(a1, b, acc[1][nt], 0, 0, 0);
        }
    }

    // C/D layout: col = lane&15, row = quad*4 + reg
    #pragma unroll
    for (int i = 0; i < 2; ++i) {
        #pragma unroll
        for (int r = 0; r < 4; ++r) {
            int gm = bm + i * 16 + quad * 4 + r;
            if (gm >= M) continue;
            #pragma unroll
            for (int nt = 0; nt < 4; ++nt) {
                int gn = ((ng0 + nt) << 4) + l15;
                if (gn >= N) continue;
                float s = acc[i][nt][r] + bias[gn];
                Y[(size_t)gm * N + gn] = 1.0f / (1.0f + expf(-s));
            }
        }
    }
}

// ---------------------------------------------------------------- adjacency expansion (float4 stores)
__global__ __launch_bounds__(256) void k_adj(const float* __restrict__ probs,
                                             float* __restrict__ adj) {
    int i = blockIdx.x * blockDim.x + threadIdx.x;   // (g, a, b4): 200*100*25
    if (i >= N_GRAPHS * MAXN * (MAXN / 4)) return;
    int b4 = (i % (MAXN / 4)) * 4;
    int a  = (i / (MAXN / 4)) % MAXN;
    int g  = i / (MAXN * (MAXN / 4));
    const float* pg = probs + (size_t)g * P_PAIRS;
    float4 o;
    float* op = (float*)&o;
    #pragma unroll
    for (int c = 0; c < 4; ++c) {
        int b = b4 + c;
        float v = 0.0f;
        if (a != b) {
            int lo = min(a, b), hi = max(a, b);
            int p = lo * (MAXN - 1) - (lo * (lo - 1)) / 2 + (hi - lo - 1);
            v = pg[p];
        }
        op[c] = v;
    }
    ((float4*)adj)[i] = o;
}

// ================================================================ launch
extern "C" void kernel_launch(void* const* d_in, const int* in_sizes, int n_in,
                              void* d_out, int out_size, void* d_ws, size_t ws_size,
                              hipStream_t stream) {
    const float* x    = (const float*)d_in[0];
    const int*   eidx = (const int*)d_in[1];
    const int*   batch= (const int*)d_in[2];
    const float* eps  = (const float*)d_in[3];
    const float* W1   = (const float*)d_in[4];
    const float* b1   = (const float*)d_in[5];
    const float* W2   = (const float*)d_in[6];
    const float* b2   = (const float*)d_in[7];
    const float* Wmu  = (const float*)d_in[8];
    const float* bmu  = (const float*)d_in[9];
    const float* Wlv  = (const float*)d_in[10];
    const float* blv  = (const float*)d_in[11];
    const float* D1   = (const float*)d_in[12];
    const float* db1  = (const float*)d_in[13];
    const float* D2   = (const float*)d_in[14];
    const float* db2  = (const float*)d_in[15];
    const float* D3   = (const float*)d_in[16];
    const float* db3  = (const float*)d_in[17];

    const int* src = eidx;
    const int* dst = eidx + N_EDGES;
    float* out = (float*)d_out;

    // workspace carve-up (fill + hg contiguous -> single memset)
    char* wsb = (char*)d_ws;
    size_t o = 0;
    auto carve = [&](size_t bytes) { void* p = wsb + o; o += (bytes + 255) & ~255ull; return p; };
    int*   fill   = (int*)  carve(N_NODES * sizeof(int));                  // 80128
    float* hg     = (float*)carve((size_t)N_GRAPHS * F_H * sizeof(float)); // 204800
    int*   ell    = (int*)  carve((size_t)N_NODES * ELL_W * sizeof(int));  // 5.12 MB
    float* dinv   = (float*)carve(N_NODES * sizeof(float));
    unsigned short* xs  = (unsigned short*)carve((size_t)N_NODES * F_IN * sizeof(short));
    unsigned short* W1p = (unsigned short*)carve((size_t)F_IN * F_H * sizeof(short));
    unsigned short* W2p = (unsigned short*)carve((size_t)F_H * F_H * sizeof(short));
    unsigned short* D3p = (unsigned short*)carve((size_t)F_H * P_PAD * sizeof(short));
    unsigned short* h1s = (unsigned short*)carve((size_t)N_NODES * F_H * sizeof(short));  // dinv*h1
    unsigned short* g2  = (unsigned short*)carve((size_t)N_NODES * F_H * sizeof(short));  // agg h1
    unsigned short* d2b = (unsigned short*)carve((size_t)N_GRAPHS * F_H * sizeof(short));
    float* probs  = (float*)carve((size_t)N_GRAPHS * P_PAIRS * sizeof(float));

    // ---- ELL build + prepack (fill+hg zeroed in one contiguous memset)
    hipMemsetAsync(fill, 0, 284928, stream);
    k_fill_prepack<<<EF_NB + PP_NB, 256, 0, stream>>>(src, dst, fill, ell,
                                                      W1, W2, D3, W1p, W2p, D3p);
    k_dinv_xs<<<DV_NB + CV_NB, 256, 0, stream>>>(fill, dinv, x, xs);

    // ---- GCN layer 1: fused gather(x) + MFMA transform (LDS A-tile)
    k_layer1<<<ceil_div(N_NODES, 64), 512, 0, stream>>>(xs, fill, ell, dinv,
                                                        W1p, b1, h1s, N_NODES);

    // ---- GCN layer 2: aggregate h1s (256 feats), then MFMA + fused mean-pool sums
    k_gather2<<<N_NODES / 4, 512, 0, stream>>>(h1s, fill, ell, dinv, g2);
    {
        dim3 grid(F_H / 64, ceil_div(N_NODES, 128));
        k_gemm_pool<<<grid, 256, 0, stream>>>(g2, W2p, b2, batch, hg, N_NODES);
    }

    // ---- head/dec1/dec2 (divides hg sums by per-graph count)
    k_head_dec<<<N_GRAPHS, 256, 0, stream>>>(hg, batch, Wmu, bmu, Wlv, blv, eps,
                                             D1, db1, D2, db2, out, d2b);

    // ---- decoder D3 (MFMA, sigmoid -> probs)
    {
        dim3 grid(P_PAD / 64, ceil_div(N_GRAPHS, 128));
        k_gemm3<<<grid, 256, 0, stream>>>(d2b, D3p, probs, db3,
                                          N_GRAPHS, P_PAIRS, P_PAD);
    }

    // ---- adjacency expansion (vec4)
    k_adj<<<ceil_div(N_GRAPHS * MAXN * (MAXN / 4), 256), 256, 0, stream>>>(probs, out);
}